// Round 3
// baseline (1093.501 us; speedup 1.0000x reference)
//
#include <hip/hip_runtime.h>

__device__ __forceinline__ float silu_f(float v) {
    return v * __builtin_amdgcn_rcpf(1.0f + __expf(-v));
}

// 3x3 conv, pad=1, stride S. Block: TXxTY output tile x CO output channels.
// CST input channels staged per barrier round (zero-padded via clamp+mask,
// staging descriptors hoisted out of the channel loop).
// Weights OIHW [CoutTotal][CIN][3][3]. Fused SiLU + optional residual.
template <int CIN, int CST, int CO, int S, int TX, int TY, bool RESID>
__global__ __launch_bounds__(256, 4) void conv3x3_v2(
    const float* __restrict__ in, long inNStride,
    const float* __restrict__ w, const float* __restrict__ bias,
    float* __restrict__ out, long outNStride,
    const float* __restrict__ resid, long residNStride,
    int Hin, int Win, int Hout, int Wout)
{
    constexpr int ITX = (TX - 1) * S + 3;
    constexpr int ITY = (TY - 1) * S + 3;
    constexpr int ITN = ITX * ITY;
    constexpr int NSLOT = (ITN + 255) / 256;
    __shared__ float tile[CST][ITN];

    const int tid = threadIdx.x;
    const int tilesx = Wout / TX;
    const int bx = blockIdx.x % tilesx;
    const int by = blockIdx.x / tilesx;
    const int co0 = blockIdx.y * CO;
    const int n  = blockIdx.z;

    const int tx = tid % TX, ty = tid / TX;
    const int ox = bx * TX + tx, oy = by * TY + ty;
    const int ix0 = bx * TX * S - 1, iy0 = by * TY * S - 1;

    // Hoisted staging descriptors: clamped global offset + validity mask.
    int   soff[NSLOT];
    float smask[NSLOT];
    #pragma unroll
    for (int s = 0; s < NSLOT; ++s) {
        const int t  = tid + s * 256;
        const int ly = t / ITX, lx = t - ly * ITX;
        const int iy = iy0 + ly, ix = ix0 + lx;
        const bool ok = (t < ITN) && iy >= 0 && iy < Hin && ix >= 0 && ix < Win;
        const int cy = min(max(iy, 0), Hin - 1);
        const int cx = min(max(ix, 0), Win - 1);
        soff[s]  = cy * Win + cx;
        smask[s] = ok ? 1.0f : 0.0f;
    }

    float acc[CO];
    #pragma unroll
    for (int j = 0; j < CO; ++j) acc[j] = bias[co0 + j];

    const float* ip = in + (long)n * inNStride;

    for (int c0 = 0; c0 < CIN; c0 += CST) {
        __syncthreads();
        #pragma unroll
        for (int c = 0; c < CST; ++c) {
            const float* plane = ip + (long)(c0 + c) * Hin * Win;
            #pragma unroll
            for (int s = 0; s < NSLOT; ++s) {
                const int t = tid + s * 256;
                if (t < ITN) tile[c][t] = plane[soff[s]] * smask[s];
            }
        }
        __syncthreads();

        #pragma unroll
        for (int c = 0; c < CST; ++c) {
            float v[9];
            #pragma unroll
            for (int ky = 0; ky < 3; ++ky)
                #pragma unroll
                for (int kx = 0; kx < 3; ++kx)
                    v[ky * 3 + kx] = tile[c][(ty * S + ky) * ITX + tx * S + kx];

            const float* wp = w + ((long)co0 * CIN + (c0 + c)) * 9;
            #pragma unroll
            for (int j = 0; j < CO; ++j) {
                const float* w9 = wp + (long)j * CIN * 9;   // uniform -> s_load
                #pragma unroll
                for (int k = 0; k < 9; ++k) acc[j] += v[k] * w9[k];
            }
        }
    }

    const long HW = (long)Hout * Wout;
    float* op = out + (long)n * outNStride + (long)co0 * HW + (long)oy * Wout + ox;
    const float* rp = nullptr;
    if (RESID)
        rp = resid + (long)n * residNStride + (long)oy * Wout + ox;
    #pragma unroll
    for (int j = 0; j < CO; ++j) {
        float r = silu_f(acc[j]);
        if (RESID) r += rp[(long)(co0 + j) * HW];
        op[(long)j * HW] = r;
    }
}

// 1x1 conv over (optionally concatenated) NCHW input. Thread = one pixel,
// CO output channels in registers; input read in 32-channel register chunks.
template <int CIN1, int CIN2, int CO>
__global__ __launch_bounds__(256) void conv1x1_k(
    const float* __restrict__ in1, long n1s,
    const float* __restrict__ in2, long n2s,
    const float* __restrict__ w, const float* __restrict__ bias,
    float* __restrict__ out, long onS, int HW)
{
    constexpr int CIN = CIN1 + CIN2;
    const int p   = blockIdx.x * 256 + threadIdx.x;
    const int co0 = blockIdx.y * CO;
    const int n   = blockIdx.z;

    float acc[CO];
    #pragma unroll
    for (int j = 0; j < CO; ++j) acc[j] = bias[co0 + j];

    const float* p1 = in1 + (long)n * n1s + p;
    const float* p2 = in2 + (long)n * n2s + p;

    #pragma unroll
    for (int cc = 0; cc < CIN; cc += 32) {
        float v[32];
        #pragma unroll
        for (int k = 0; k < 32; ++k) {
            const int ci = cc + k;
            v[k] = (ci < CIN1) ? p1[(long)ci * HW]
                               : p2[(long)(ci - CIN1) * HW];
        }
        #pragma unroll
        for (int j = 0; j < CO; ++j) {
            const float* wr = w + (long)(co0 + j) * CIN + cc;  // uniform
            #pragma unroll
            for (int k = 0; k < 32; ++k) acc[j] += v[k] * wr[k];
        }
    }

    float* op = out + (long)n * onS + (long)co0 * HW + p;
    #pragma unroll
    for (int j = 0; j < CO; ++j) op[(long)j * HW] = silu_f(acc[j]);
}

extern "C" void kernel_launch(void* const* d_in, const int* in_sizes, int n_in,
                              void* d_out, int out_size, void* d_ws, size_t ws_size,
                              hipStream_t stream) {
    const float* x   = (const float*)d_in[0];
    const float* w0  = (const float*)d_in[1];
    const float* b0  = (const float*)d_in[2];
    const float* w1  = (const float*)d_in[3];
    const float* b1  = (const float*)d_in[4];
    const float* wc0 = (const float*)d_in[5];
    const float* bc0 = (const float*)d_in[6];
    const float* wb1 = (const float*)d_in[7];
    const float* bb1 = (const float*)d_in[8];
    const float* wb2 = (const float*)d_in[9];
    const float* bb2 = (const float*)d_in[10];
    const float* wc1 = (const float*)d_in[11];
    const float* bc1 = (const float*)d_in[12];
    const float* w3  = (const float*)d_in[13];
    const float* b3  = (const float*)d_in[14];
    float* out = (float*)d_out;
    float* ws  = (float*)d_ws;

    // Workspace (floats), peak 39,321,600 = 157.3 MB:
    //   h0 [8,32,320,320] @0 ; h1 [8,64,160,160] @26214400
    //   y  @0 ; b1f @13107200 ; bf @19660800 ; h2 @26214400 (reuse)
    float* h0  = ws;
    float* h1  = ws + 26214400L;
    float* yb  = ws;
    float* b1f = ws + 13107200L;
    float* bf  = ws + 19660800L;
    float* h2  = ws + 26214400L;

    const dim3 blk(256, 1, 1);
    const long HW1 = 25600;       // 160*160

    // conv0: 3->32, s2, 640->320. CST=3 (single round), 3200 blocks.
    conv3x3_v2<3, 3, 32, 2, 16, 16, false><<<dim3(400, 1, 8), blk, 0, stream>>>(
        x, 3L * 640 * 640, w0, b0, h0, 32L * 320 * 320, nullptr, 0,
        640, 640, 320, 320);

    // conv1: 32->64, s2, 320->160. CO=16 x4 chunks -> 3200 blocks.
    conv3x3_v2<32, 2, 16, 2, 16, 16, false><<<dim3(100, 4, 8), blk, 0, stream>>>(
        h0, 32L * 320 * 320, w1, b1, h1, 64L * HW1, nullptr, 0,
        320, 320, 160, 160);

    // wc0: 1x1 64->64 on h1 -> y. 1600 blocks.
    conv1x1_k<64, 0, 32><<<dim3(100, 2, 8), blk, 0, stream>>>(
        h1, 64L * HW1, h1, 64L * HW1, wc0, bc0, yb, 64L * HW1, (int)HW1);

    // wb1: 3x3 s1 32->32 on x2 (= y ch 32..63) -> b1f. CO=16 x2 -> 1600 blocks.
    conv3x3_v2<32, 4, 16, 1, 16, 16, false><<<dim3(100, 2, 8), blk, 0, stream>>>(
        yb + 32 * HW1, 64L * HW1, wb1, bb1, b1f, 32L * HW1, nullptr, 0,
        160, 160, 160, 160);

    // wb2: 3x3 s1 32->32 on b1f, + residual x2 -> bf. 1600 blocks.
    conv3x3_v2<32, 4, 16, 1, 16, 16, true><<<dim3(100, 2, 8), blk, 0, stream>>>(
        b1f, 32L * HW1, wb2, bb2, bf, 32L * HW1, yb + 32 * HW1, 64L * HW1,
        160, 160, 160, 160);

    // wc1: 1x1 on concat([y(64), bf(32)]) -> 64 -> h2. 1600 blocks.
    conv1x1_k<64, 32, 32><<<dim3(100, 2, 8), blk, 0, stream>>>(
        yb, 64L * HW1, bf, 32L * HW1, wc1, bc1, h2, 64L * HW1, (int)HW1);

    // conv3: 3x3 s2 64->128, 160->80. CO=16 x8 chunks -> 1600 blocks.
    conv3x3_v2<64, 2, 16, 2, 16, 16, false><<<dim3(25, 8, 8), blk, 0, stream>>>(
        h2, 64L * HW1, w3, b3, out, 128L * 6400, nullptr, 0,
        160, 160, 80, 80);
}

// Round 4
// 554.239 us; speedup vs baseline: 1.9730x; 1.9730x over previous
//
#include <hip/hip_runtime.h>
#include <hip/hip_bf16.h>

typedef __attribute__((ext_vector_type(8))) short short8;
typedef __attribute__((ext_vector_type(4))) float f32x4;
typedef __attribute__((ext_vector_type(4))) unsigned int uint4v;

__device__ __forceinline__ float silu_f(float v) {
    return v * __builtin_amdgcn_rcpf(1.0f + __expf(-v));
}
__device__ __forceinline__ unsigned short bfhi(float v) {
    __hip_bfloat16 h = __float2bfloat16(v);
    return *reinterpret_cast<unsigned short*>(&h);
}
__device__ __forceinline__ float bf2f(unsigned short u) {
    __hip_bfloat16 h;
    *reinterpret_cast<unsigned short*>(&h) = u;
    return __bfloat162float(h);
}

// ---------------- conv0: 3->32 s2, f32 direct, writes channel-last hi/lo ----
__global__ __launch_bounds__(256) void conv0_cl(
    const float* __restrict__ x, const float* __restrict__ w,
    const float* __restrict__ bias, unsigned short* __restrict__ out)
{
    const int tid = threadIdx.x;
    const int px = blockIdx.x * 256 + tid;        // 0..102399
    const int n = blockIdx.z;
    const int y = px / 320, xx = px % 320;

    float acc[32];
    #pragma unroll
    for (int j = 0; j < 32; ++j) acc[j] = bias[j];

    const float* xp = x + (long)n * 3 * 409600;
    #pragma unroll
    for (int ci = 0; ci < 3; ++ci) {
        const float* plane = xp + (long)ci * 409600;
        float v[9];
        #pragma unroll
        for (int ky = 0; ky < 3; ++ky) {
            const int iy = 2 * y + ky - 1;
            const bool yok = (iy >= 0) && (iy < 640);
            const int cy = yok ? iy : 0;
            #pragma unroll
            for (int kx = 0; kx < 3; ++kx) {
                const int ix = 2 * xx + kx - 1;
                const bool ok = yok && (ix >= 0) && (ix < 640);
                const int cx = ok ? ix : 0;
                float t = plane[(long)cy * 640 + cx];
                v[ky * 3 + kx] = ok ? t : 0.0f;
            }
        }
        #pragma unroll
        for (int co = 0; co < 32; ++co) {
            const float* w9 = w + (co * 3 + ci) * 9;
            #pragma unroll
            for (int k = 0; k < 9; ++k) acc[co] += v[k] * w9[k];
        }
    }
    unsigned short* op = out + ((long)n * 102400 + px) * 64;
    #pragma unroll
    for (int g = 0; g < 4; ++g) {
        unsigned int hw[4], lw[4];
        #pragma unroll
        for (int p2 = 0; p2 < 4; ++p2) {
            float v0 = silu_f(acc[g * 8 + p2 * 2]);
            float v1 = silu_f(acc[g * 8 + p2 * 2 + 1]);
            unsigned short h0 = bfhi(v0), h1 = bfhi(v1);
            unsigned short l0 = bfhi(v0 - bf2f(h0)), l1 = bfhi(v1 - bf2f(h1));
            hw[p2] = (unsigned)h0 | ((unsigned)h1 << 16);
            lw[p2] = (unsigned)l0 | ((unsigned)l1 << 16);
        }
        *reinterpret_cast<uint4v*>(op + g * 16)     = uint4v{hw[0], hw[1], hw[2], hw[3]};
        *reinterpret_cast<uint4v*>(op + g * 16 + 8) = uint4v{lw[0], lw[1], lw[2], lw[3]};
    }
}

// ---------------- generic conv as tap-GEMM, bf16x2 MFMA ---------------------
// Input(s): channel-last hi/lo granules (32B = 8 hi bf16 + 8 lo bf16).
// row16_*: ushorts per pixel row (CIN*4/2). Weights: raw f32 OIHW, converted
// to LDS granules per block (XOR-swizzled). Block: 4 waves x 64 px; wave does
// 4 px-chunks x (COW) output channels. TAPS=9 (3x3) or 1 (1x1).
template <int NC1, int NC2, int COW, int TAPS, int S, bool RESID, bool F32OUT>
__global__ __launch_bounds__(256) void gemm_conv(
    const unsigned short* __restrict__ in1, int row16_1,
    const unsigned short* __restrict__ in2, int row16_2,
    const float* __restrict__ wraw, const float* __restrict__ bias,
    void* __restrict__ outp, int ngout,
    const unsigned short* __restrict__ resid,
    int Hin, int Win, int Hout, int Wout, int COtot)
{
    constexpr int NCIC = NC1 + NC2;
    constexpr int CINT = NCIC * 32;
    constexpr int NCC = COW / 16;
    __shared__ unsigned short lds_w[TAPS * NCIC * COW * 64];

    const int tid = threadIdx.x;
    const int lane = tid & 63;
    const int wid = tid >> 6;
    const int lm = lane & 15, lg = lane >> 4;
    const int co0 = blockIdx.y * COW;
    const int n = blockIdx.z;

    // ---- stage this block's weights into LDS as hi/lo granules ----
    const int G = TAPS * NCIC * COW * 4;
    for (int e = tid; e < G; e += 256) {
        const int glg = e & 3;
        const int co = (e >> 2) % COW;
        const int tc = (e >> 2) / COW;          // tap*NCIC + cic
        const int cic = tc % NCIC, tap = tc / NCIC;
        unsigned short* dst = &lds_w[(tc * COW + co) * 64 + ((glg ^ (co & 3)) * 16)];
        #pragma unroll
        for (int j = 0; j < 8; ++j) {
            const int ci = cic * 32 + glg * 8 + j;
            float wv = wraw[((long)(co0 + co) * CINT + ci) * TAPS + tap];
            unsigned short h = bfhi(wv);
            dst[j] = h;
            dst[8 + j] = bfhi(wv - bf2f(h));
        }
    }
    __syncthreads();

    const int pxw0 = blockIdx.x * 256 + wid * 64;
    const long inNS1 = (long)Hin * Win * row16_1;
    const long inNS2 = (long)Hin * Win * row16_2;
    const unsigned short* p1 = in1 + (long)n * inNS1;
    const unsigned short* p2 = in2 ? in2 + (long)n * inNS2 : nullptr;

    f32x4 acc[4][NCC];
    #pragma unroll
    for (int cc = 0; cc < NCC; ++cc) {
        float bv = bias[co0 + cc * 16 + lm];
        #pragma unroll
        for (int c = 0; c < 4; ++c) acc[c][cc] = f32x4{bv, bv, bv, bv};
    }

    int ycs[4], xc0s[4];
    #pragma unroll
    for (int c = 0; c < 4; ++c) {
        int pc = pxw0 + c * 16;
        ycs[c] = pc / Wout; xc0s[c] = pc % Wout;
    }

    for (int tap = 0; tap < TAPS; ++tap) {
        const int dy = (TAPS == 9) ? (tap / 3 - 1) : 0;
        const int dx = (TAPS == 9) ? (tap % 3 - 1) : 0;
        #pragma unroll
        for (int cic = 0; cic < NCIC; ++cic) {
            short8 bhi[NCC], blo[NCC];
            #pragma unroll
            for (int cc = 0; cc < NCC; ++cc) {
                const int col = cc * 16 + lm;
                const unsigned short* s =
                    &lds_w[((tap * NCIC + cic) * COW + col) * 64 + ((lg ^ (col & 3)) * 16)];
                bhi[cc] = *reinterpret_cast<const short8*>(s);
                blo[cc] = *reinterpret_cast<const short8*>(s + 8);
            }
            const bool part1 = (cic < NC1);
            const unsigned short* pb = part1 ? p1 : p2;
            const int r16 = part1 ? row16_1 : row16_2;
            const int goff = (part1 ? cic : cic - NC1) * 64 + lg * 16;
            #pragma unroll
            for (int c = 0; c < 4; ++c) {
                const int yq = ycs[c] * S + dy;
                if (TAPS == 9) { if (yq < 0 || yq >= Hin) continue; }
                const int xq = (xc0s[c] + lm) * S + dx;
                bool xok = true; int xc = xq;
                if (TAPS == 9) { xok = (xq >= 0) && (xq < Win); xc = xok ? xq : 0; }
                const unsigned short* ap = pb + ((long)yq * Win + xc) * r16 + goff;
                short8 ahi = *reinterpret_cast<const short8*>(ap);
                short8 alo = *reinterpret_cast<const short8*>(ap + 8);
                if (TAPS == 9 && !xok) { ahi = (short8)0; alo = (short8)0; }
                #pragma unroll
                for (int cc = 0; cc < NCC; ++cc) {
                    acc[c][cc] = __builtin_amdgcn_mfma_f32_16x16x32_bf16(ahi, bhi[cc], acc[c][cc], 0, 0, 0);
                    acc[c][cc] = __builtin_amdgcn_mfma_f32_16x16x32_bf16(ahi, blo[cc], acc[c][cc], 0, 0, 0);
                    acc[c][cc] = __builtin_amdgcn_mfma_f32_16x16x32_bf16(alo, bhi[cc], acc[c][cc], 0, 0, 0);
                }
            }
        }
    }

    const long HWo = (long)Hout * Wout;
    #pragma unroll
    for (int c = 0; c < 4; ++c) {
        #pragma unroll
        for (int cc = 0; cc < NCC; ++cc) {
            const int co = co0 + cc * 16 + lm;
            #pragma unroll
            for (int r = 0; r < 4; ++r) {
                const int pxo = pxw0 + c * 16 + lg * 4 + r;
                float v = silu_f(acc[c][cc][r]);
                if (RESID) {
                    const unsigned short* rp = resid + (long)n * HWo * 128 + (long)pxo * 128
                                               + ((32 + co) >> 3) * 16 + ((32 + co) & 7);
                    v += bf2f(rp[0]) + bf2f(rp[8]);
                }
                if (F32OUT) {
                    ((float*)outp)[((long)n * COtot + co) * HWo + pxo] = v;
                } else {
                    unsigned short* q = (unsigned short*)outp
                        + ((long)n * HWo + pxo) * (ngout * 16) + (co >> 3) * 16 + (co & 7);
                    unsigned short h = bfhi(v);
                    q[0] = h; q[8] = bfhi(v - bf2f(h));
                }
            }
        }
    }
}

extern "C" void kernel_launch(void* const* d_in, const int* in_sizes, int n_in,
                              void* d_out, int out_size, void* d_ws, size_t ws_size,
                              hipStream_t stream) {
    const float* x   = (const float*)d_in[0];
    const float* w0  = (const float*)d_in[1];
    const float* b0  = (const float*)d_in[2];
    const float* w1  = (const float*)d_in[3];
    const float* b1  = (const float*)d_in[4];
    const float* wc0 = (const float*)d_in[5];
    const float* bc0 = (const float*)d_in[6];
    const float* wb1 = (const float*)d_in[7];
    const float* bb1 = (const float*)d_in[8];
    const float* wb2 = (const float*)d_in[9];
    const float* bb2 = (const float*)d_in[10];
    const float* wc1 = (const float*)d_in[11];
    const float* bc1 = (const float*)d_in[12];
    const float* w3  = (const float*)d_in[13];
    const float* b3  = (const float*)d_in[14];

    unsigned short* u = (unsigned short*)d_ws;
    // ushort offsets; peak = 157,286,400 bytes (same as prior rounds)
    unsigned short* h0cl = u;                    // 8*102400 px * 64  (32ci hi/lo)
    unsigned short* h1cl = u + 52428800L;        // 8*25600 px * 128 (64ci)
    unsigned short* ycl  = u;                    // reuse h0cl
    unsigned short* b1cl = u + 26214400L;        // 8*25600*64 (32ci)
    unsigned short* bcl  = u + 39321600L;        // 8*25600*64 (32ci)
    unsigned short* h2cl = u + 52428800L;        // reuse h1cl

    const dim3 blk(256, 1, 1);

    // conv0: 3->32 s2 (f32 direct) -> h0cl
    conv0_cl<<<dim3(400, 1, 8), blk, 0, stream>>>(x, w0, b0, h0cl);

    // conv1: 32->64 s2, 3x3 -> h1cl
    gemm_conv<1, 0, 32, 9, 2, false, false><<<dim3(100, 2, 8), blk, 0, stream>>>(
        h0cl, 64, nullptr, 0, w1, b1, h1cl, 8, nullptr, 320, 320, 160, 160, 64);

    // wc0: 64->64 1x1 -> ycl
    gemm_conv<2, 0, 32, 1, 1, false, false><<<dim3(100, 2, 8), blk, 0, stream>>>(
        h1cl, 128, nullptr, 0, wc0, bc0, ycl, 8, nullptr, 160, 160, 160, 160, 64);

    // wb1: 32->32 3x3 on x2 (ycl ci 32..63) -> b1cl
    gemm_conv<1, 0, 16, 9, 1, false, false><<<dim3(100, 2, 8), blk, 0, stream>>>(
        ycl + 64, 128, nullptr, 0, wb1, bb1, b1cl, 4, nullptr, 160, 160, 160, 160, 32);

    // wb2: 32->32 3x3 on b1cl, + resid x2 -> bcl
    gemm_conv<1, 0, 16, 9, 1, true, false><<<dim3(100, 2, 8), blk, 0, stream>>>(
        b1cl, 64, nullptr, 0, wb2, bb2, bcl, 4, ycl, 160, 160, 160, 160, 32);

    // wc1: concat(ycl 64ci, bcl 32ci) -> 64, 1x1 -> h2cl
    gemm_conv<2, 1, 32, 1, 1, false, false><<<dim3(100, 2, 8), blk, 0, stream>>>(
        ycl, 128, bcl, 64, wc1, bc1, h2cl, 8, nullptr, 160, 160, 160, 160, 64);

    // conv3: 64->128 s2 3x3 -> d_out (f32 NCHW)
    gemm_conv<2, 0, 16, 9, 2, false, true><<<dim3(25, 8, 8), blk, 0, stream>>>(
        h2cl, 128, nullptr, 0, w3, b3, d_out, 0, nullptr, 160, 160, 80, 80, 128);
}

// Round 5
// 459.406 us; speedup vs baseline: 2.3803x; 1.2064x over previous
//
#include <hip/hip_runtime.h>
#include <hip/hip_bf16.h>

typedef __attribute__((ext_vector_type(8))) short short8;
typedef __attribute__((ext_vector_type(16))) float f32x16;
typedef __attribute__((ext_vector_type(4))) float f32x4;
typedef __attribute__((ext_vector_type(4))) unsigned int uint4v;
typedef __attribute__((ext_vector_type(4))) unsigned short ushort4v;

__device__ __forceinline__ float silu_f(float v) {
    return v * __builtin_amdgcn_rcpf(1.0f + __expf(-v));
}
__device__ __forceinline__ unsigned short bfhi(float v) {
    __hip_bfloat16 h = __float2bfloat16(v);
    return *reinterpret_cast<unsigned short*>(&h);
}
__device__ __forceinline__ float bf2f(unsigned short u) {
    __hip_bfloat16 h;
    *reinterpret_cast<unsigned short*>(&h) = u;
    return __bfloat162float(h);
}

// ============ conv0: 3->32 s2 f32-direct, writes PARITY-SPLIT hi/lo =========
// out: [n][plane(4)][160*160][64 ush]  (32ch: granule g hi at ush g*16, lo +8)
__global__ __launch_bounds__(256) void conv0_par(
    const float* __restrict__ x, const float* __restrict__ w,
    const float* __restrict__ bias, unsigned short* __restrict__ out)
{
    const int tid = threadIdx.x;
    const int plane = blockIdx.y;
    const int pyp = plane >> 1, pxp = plane & 1;
    const int pp = blockIdx.x * 256 + tid;       // 0..25599
    const int n = blockIdx.z;
    const int Y = 2 * (pp / 160) + pyp, X = 2 * (pp % 160) + pxp;

    float acc[32];
    #pragma unroll
    for (int j = 0; j < 32; ++j) acc[j] = bias[j];

    const float* xp = x + (long)n * 3 * 409600;
    #pragma unroll
    for (int ci = 0; ci < 3; ++ci) {
        const float* pl = xp + (long)ci * 409600;
        float v[9];
        #pragma unroll
        for (int ky = 0; ky < 3; ++ky) {
            const int iy = 2 * Y + ky - 1;
            const bool yok = (iy >= 0) && (iy < 640);
            const int cy = yok ? iy : 0;
            #pragma unroll
            for (int kx = 0; kx < 3; ++kx) {
                const int ix = 2 * X + kx - 1;
                const bool ok = yok && (ix >= 0) && (ix < 640);
                float t = pl[(long)cy * 640 + (ok ? ix : 0)];
                v[ky * 3 + kx] = ok ? t : 0.0f;
            }
        }
        #pragma unroll
        for (int co = 0; co < 32; ++co) {
            const float* w9 = w + (co * 3 + ci) * 9;
            #pragma unroll
            for (int k = 0; k < 9; ++k) acc[co] += v[k] * w9[k];
        }
    }
    unsigned short* op = out + (((long)n * 4 + plane) * 25600 + pp) * 64;
    #pragma unroll
    for (int g = 0; g < 4; ++g) {
        unsigned int hw[4], lw[4];
        #pragma unroll
        for (int p2 = 0; p2 < 4; ++p2) {
            float v0 = silu_f(acc[g * 8 + p2 * 2]);
            float v1 = silu_f(acc[g * 8 + p2 * 2 + 1]);
            unsigned short h0 = bfhi(v0), h1 = bfhi(v1);
            hw[p2] = (unsigned)h0 | ((unsigned)h1 << 16);
            lw[p2] = (unsigned)bfhi(v0 - bf2f(h0)) | ((unsigned)bfhi(v1 - bf2f(h1)) << 16);
        }
        *reinterpret_cast<uint4v*>(op + g * 16)     = uint4v{hw[0], hw[1], hw[2], hw[3]};
        *reinterpret_cast<uint4v*>(op + g * 16 + 8) = uint4v{lw[0], lw[1], lw[2], lw[3]};
    }
}

// ============ conv1: 32->64 s2 3x3, parity-plane LDS tiles + MFMA ===========
// in h0 planes [n][4][25600][64ush]; out h1 [n][25600][128ush]
// block: out tile 32x8 (256px), 4 waves x 2 chunks(32px); COW=64 (cc=2)
__global__ __launch_bounds__(256, 2) void conv1_par(
    const unsigned short* __restrict__ h0, const float* __restrict__ wraw,
    const float* __restrict__ bias, unsigned short* __restrict__ h1)
{
    __shared__ unsigned short lds[72224];        // tile 35360 ush + frags 36864 ush
    const int FB = 35360;
    const int tid = threadIdx.x;
    const int wv = tid >> 6, lane = tid & 63;
    const int p = lane & 31, h = lane >> 5;
    const int bx = blockIdx.x % 5, by = blockIdx.x / 5;
    const int ox0 = bx * 32, oy0 = by * 8;
    const int n = blockIdx.z;

    // stage weight frags: pf=(tap*2+rnd)*2+cc, frag f=pf*2+kind, 1KB each
    for (int u = tid; u < 2304; u += 256) {
        const int l = u & 63, pf = u >> 6;
        const int cc = pf & 1, rnd = (pf >> 1) & 1, tap = pf >> 2;
        const int co = cc * 32 + (l & 31);
        const int ci0 = rnd * 16 + (l >> 5) * 8;
        unsigned short hs[8], ls[8];
        #pragma unroll
        for (int j = 0; j < 8; ++j) {
            float wv_ = wraw[(co * 32 + ci0 + j) * 9 + tap];
            unsigned short hh = bfhi(wv_);
            hs[j] = hh; ls[j] = bfhi(wv_ - bf2f(hh));
        }
        *reinterpret_cast<short8*>(&lds[FB + pf * 1024 + l * 8])       = *(short8*)hs;
        *reinterpret_cast<short8*>(&lds[FB + pf * 1024 + 512 + l * 8]) = *(short8*)ls;
    }

    f32x16 acc[2][2];
    #pragma unroll
    for (int cc = 0; cc < 2; ++cc)
        #pragma unroll
        for (int q = 0; q < 4; ++q) {
            f32x4 b4 = *reinterpret_cast<const f32x4*>(&bias[cc * 32 + q * 8 + 4 * h]);
            #pragma unroll
            for (int r = 0; r < 4; ++r) { acc[cc][0][q*4+r] = b4[r]; acc[cc][1][q*4+r] = b4[r]; }
        }

    for (int rnd = 0; rnd < 2; ++rnd) {
        __syncthreads();
        // stage parity tiles: ee[0,256)W32, eo[256,520)W33, oe[520,808)W32, oo[808,1105)W33
        for (int u = tid; u < 4420; u += 256) {
            const int rec = u >> 2, s = u & 3;
            int gp, row, col;
            if (rec < 256)      { gp = 0; row = rec >> 5;  col = rec & 31; }
            else if (rec < 520) { gp = 1; int r2 = rec - 256; row = r2 / 33; col = r2 - row * 33; }
            else if (rec < 808) { gp = 2; int r2 = rec - 520; row = r2 >> 5; col = r2 & 31; }
            else                { gp = 3; int r2 = rec - 808; row = r2 / 33; col = r2 - row * 33; }
            const int gr = (gp >= 2) ? oy0 - 1 + row : oy0 + row;
            const int gc = (gp & 1)  ? ox0 - 1 + col : ox0 + col;
            uint4v val = {0, 0, 0, 0};
            if (gr >= 0 && gr < 160 && gc >= 0 && gc < 160)
                val = *reinterpret_cast<const uint4v*>(
                    h0 + (((long)n * 4 + gp) * 25600 + gr * 160 + gc) * 64 + (rnd * 4 + s) * 8);
            *reinterpret_cast<uint4v*>(&lds[rec * 32 + ((s ^ (rec & 3)) * 8)]) = val;
        }
        __syncthreads();

        #pragma unroll
        for (int tap = 0; tap < 9; ++tap) {
            const int dy = tap / 3 - 1, dx = tap % 3 - 1;
            const int ppy = dy & 1, ppx = dx & 1;
            const int gp = ppy * 2 + ppx;
            const int toy = ppy ? ((dy == -1) ? 0 : 1) : 0;
            const int tox = ppx ? ((dx == -1) ? 0 : 1) : 0;
            const int base = (gp == 0) ? 0 : (gp == 1) ? 256 : (gp == 2) ? 520 : 808;
            const int W = ppx ? 33 : 32;
            short8 Bh[2], Bl[2];
            #pragma unroll
            for (int k = 0; k < 2; ++k) {
                const int c = wv * 2 + k;
                const int rec = base + (ppy ? (c + toy) : c) * W + (p + tox);
                const unsigned short* t = &lds[rec * 32];
                Bh[k] = *reinterpret_cast<const short8*>(t + (((2*h)     ^ (rec & 3)) * 8));
                Bl[k] = *reinterpret_cast<const short8*>(t + (((2*h + 1) ^ (rec & 3)) * 8));
            }
            #pragma unroll
            for (int cc = 0; cc < 2; ++cc) {
                const int pf = (tap * 2 + rnd) * 2 + cc;
                const unsigned short* fb = &lds[FB + pf * 1024 + lane * 8];
                short8 Awh = *reinterpret_cast<const short8*>(fb);
                short8 Awl = *reinterpret_cast<const short8*>(fb + 512);
                #pragma unroll
                for (int k = 0; k < 2; ++k) {
                    acc[cc][k] = __builtin_amdgcn_mfma_f32_32x32x16_bf16(Awh, Bh[k], acc[cc][k], 0, 0, 0);
                    acc[cc][k] = __builtin_amdgcn_mfma_f32_32x32x16_bf16(Awh, Bl[k], acc[cc][k], 0, 0, 0);
                    acc[cc][k] = __builtin_amdgcn_mfma_f32_32x32x16_bf16(Awl, Bh[k], acc[cc][k], 0, 0, 0);
                }
            }
        }
    }

    #pragma unroll
    for (int k = 0; k < 2; ++k) {
        const int oy = oy0 + wv * 2 + k;
        unsigned short* op = h1 + ((long)n * 25600 + (long)oy * 160 + ox0 + p) * 128;
        #pragma unroll
        for (int cc = 0; cc < 2; ++cc)
            #pragma unroll
            for (int q = 0; q < 4; ++q) {
                ushort4v hv, lv;
                #pragma unroll
                for (int r = 0; r < 4; ++r) {
                    float v = silu_f(acc[cc][k][q * 4 + r]);
                    unsigned short hh = bfhi(v);
                    hv[r] = hh; lv[r] = bfhi(v - bf2f(hh));
                }
                const int gq = cc * 4 + q;
                *reinterpret_cast<ushort4v*>(op + gq * 16 + 4 * h)     = hv;
                *reinterpret_cast<ushort4v*>(op + gq * 16 + 8 + 4 * h) = lv;
            }
    }
}

// ============ wb: 32->32 s1 3x3 (bottleneck convs), LDS tile + MFMA =========
// block: out tile 32x8, COW=32 (cc=1); in rec/slot parametrized; optional resid
template <bool RESID>
__global__ __launch_bounds__(256, 2) void wb3x3(
    const unsigned short* __restrict__ in, int inRec, int inSlot0,
    const float* __restrict__ wraw, const float* __restrict__ bias,
    unsigned short* __restrict__ outb, const unsigned short* __restrict__ resid)
{
    __shared__ unsigned short lds[40192];        // tile 340*64 ush + frags 18432 ush
    const int FB = 21760;
    const int tid = threadIdx.x;
    const int wv = tid >> 6, lane = tid & 63;
    const int p = lane & 31, h = lane >> 5;
    const int bx = blockIdx.x % 5, by = blockIdx.x / 5;
    const int ox0 = bx * 32, oy0 = by * 8;
    const int n = blockIdx.z;

    for (int u = tid; u < 1152; u += 256) {      // pf = tap*2+rnd (18) x 64
        const int l = u & 63, pf = u >> 6;
        const int rnd = pf & 1, tap = pf >> 1;
        const int co = l & 31;
        const int ci0 = rnd * 16 + (l >> 5) * 8;
        unsigned short hs[8], ls[8];
        #pragma unroll
        for (int j = 0; j < 8; ++j) {
            float wv_ = wraw[(co * 32 + ci0 + j) * 9 + tap];
            unsigned short hh = bfhi(wv_);
            hs[j] = hh; ls[j] = bfhi(wv_ - bf2f(hh));
        }
        *reinterpret_cast<short8*>(&lds[FB + pf * 1024 + l * 8])       = *(short8*)hs;
        *reinterpret_cast<short8*>(&lds[FB + pf * 1024 + 512 + l * 8]) = *(short8*)ls;
    }
    // stage tile 34x10, 8 slots per rec (both rounds)
    for (int u = tid; u < 2720; u += 256) {
        const int rec = u >> 3, s = u & 7;
        const int row = rec / 34, col = rec - row * 34;
        const int gr = oy0 - 1 + row, gc = ox0 - 1 + col;
        uint4v val = {0, 0, 0, 0};
        if (gr >= 0 && gr < 160 && gc >= 0 && gc < 160)
            val = *reinterpret_cast<const uint4v*>(
                in + ((long)n * 25600 + gr * 160 + gc) * inRec + (inSlot0 + s) * 8);
        *reinterpret_cast<uint4v*>(&lds[rec * 64 + ((s ^ (rec & 7)) * 8)]) = val;
    }

    f32x16 acc[2];
    #pragma unroll
    for (int q = 0; q < 4; ++q) {
        f32x4 b4 = *reinterpret_cast<const f32x4*>(&bias[q * 8 + 4 * h]);
        #pragma unroll
        for (int r = 0; r < 4; ++r) { acc[0][q*4+r] = b4[r]; acc[1][q*4+r] = b4[r]; }
    }
    __syncthreads();

    #pragma unroll
    for (int tap = 0; tap < 9; ++tap) {
        const int dy = tap / 3 - 1, dx = tap % 3 - 1;
        short8 Bh[2][2], Bl[2][2];
        #pragma unroll
        for (int k = 0; k < 2; ++k) {
            const int c = wv * 2 + k;
            const int rec = (c + dy + 1) * 34 + (p + dx + 1);
            const unsigned short* t = &lds[rec * 64];
            #pragma unroll
            for (int rnd = 0; rnd < 2; ++rnd) {
                Bh[k][rnd] = *reinterpret_cast<const short8*>(t + (((rnd*4 + 2*h)     ^ (rec & 7)) * 8));
                Bl[k][rnd] = *reinterpret_cast<const short8*>(t + (((rnd*4 + 2*h + 1) ^ (rec & 7)) * 8));
            }
        }
        #pragma unroll
        for (int rnd = 0; rnd < 2; ++rnd) {
            const unsigned short* fb = &lds[FB + (tap * 2 + rnd) * 1024 + lane * 8];
            short8 Awh = *reinterpret_cast<const short8*>(fb);
            short8 Awl = *reinterpret_cast<const short8*>(fb + 512);
            #pragma unroll
            for (int k = 0; k < 2; ++k) {
                acc[k] = __builtin_amdgcn_mfma_f32_32x32x16_bf16(Awh, Bh[k][rnd], acc[k], 0, 0, 0);
                acc[k] = __builtin_amdgcn_mfma_f32_32x32x16_bf16(Awh, Bl[k][rnd], acc[k], 0, 0, 0);
                acc[k] = __builtin_amdgcn_mfma_f32_32x32x16_bf16(Awl, Bh[k][rnd], acc[k], 0, 0, 0);
            }
        }
    }

    #pragma unroll
    for (int k = 0; k < 2; ++k) {
        const int oy = oy0 + wv * 2 + k;
        const long prow = (long)n * 25600 + (long)oy * 160 + ox0 + p;
        unsigned short* op = outb + prow * 64;
        const unsigned short* rp = RESID ? resid + prow * 128 : nullptr;
        #pragma unroll
        for (int q = 0; q < 4; ++q) {
            ushort4v hv, lv;
            float vs[4];
            #pragma unroll
            for (int r = 0; r < 4; ++r) vs[r] = silu_f(acc[k][q * 4 + r]);
            if (RESID) {
                ushort4v rh = *reinterpret_cast<const ushort4v*>(rp + (q + 4) * 16 + 4 * h);
                ushort4v rl = *reinterpret_cast<const ushort4v*>(rp + (q + 4) * 16 + 8 + 4 * h);
                #pragma unroll
                for (int r = 0; r < 4; ++r) vs[r] += bf2f(rh[r]) + bf2f(rl[r]);
            }
            #pragma unroll
            for (int r = 0; r < 4; ++r) {
                unsigned short hh = bfhi(vs[r]);
                hv[r] = hh; lv[r] = bfhi(vs[r] - bf2f(hh));
            }
            *reinterpret_cast<ushort4v*>(op + q * 16 + 4 * h)     = hv;
            *reinterpret_cast<ushort4v*>(op + q * 16 + 8 + 4 * h) = lv;
        }
    }
}

// ============ 1x1 convs (wc0, wc1): direct global B-frags, COW=64 ===========
template <int R1, int R2, bool POUT>
__global__ __launch_bounds__(256, 2) void wc1x1(
    const unsigned short* __restrict__ in1, int rec1,
    const unsigned short* __restrict__ in2, int rec2,
    const float* __restrict__ wraw, const float* __restrict__ bias,
    unsigned short* __restrict__ outb)
{
    constexpr int RT = R1 + R2;
    constexpr int CIN = RT * 16;
    __shared__ unsigned short frg[RT * 2 * 1024];
    const int tid = threadIdx.x;
    const int wv = tid >> 6, lane = tid & 63;
    const int p = lane & 31, h = lane >> 5;
    const int n = blockIdx.z;
    const int px0 = blockIdx.x * 256;

    for (int u = tid; u < RT * 2 * 64; u += 256) {
        const int l = u & 63, pf = u >> 6;       // pf = rnd*2+cc
        const int cc = pf & 1, rnd = pf >> 1;
        const int co = cc * 32 + (l & 31);
        const int ci0 = rnd * 16 + (l >> 5) * 8;
        unsigned short hs[8], ls[8];
        #pragma unroll
        for (int j = 0; j < 8; ++j) {
            float w = wraw[co * CIN + ci0 + j];
            unsigned short hh = bfhi(w);
            hs[j] = hh; ls[j] = bfhi(w - bf2f(hh));
        }
        *reinterpret_cast<short8*>(&frg[pf * 1024 + l * 8])       = *(short8*)hs;
        *reinterpret_cast<short8*>(&frg[pf * 1024 + 512 + l * 8]) = *(short8*)ls;
    }
    __syncthreads();

    f32x16 acc[2][2];
    #pragma unroll
    for (int cc = 0; cc < 2; ++cc)
        #pragma unroll
        for (int q = 0; q < 4; ++q) {
            f32x4 b4 = *reinterpret_cast<const f32x4*>(&bias[cc * 32 + q * 8 + 4 * h]);
            #pragma unroll
            for (int r = 0; r < 4; ++r) { acc[cc][0][q*4+r] = b4[r]; acc[cc][1][q*4+r] = b4[r]; }
        }

    #pragma unroll
    for (int rnd = 0; rnd < RT; ++rnd) {
        const unsigned short* bp = (rnd < R1) ? in1 : in2;
        const int recN = (rnd < R1) ? rec1 : rec2;
        const int s0 = 4 * ((rnd < R1) ? rnd : rnd - R1);
        #pragma unroll
        for (int k = 0; k < 2; ++k) {
            const int px = px0 + (wv * 2 + k) * 32 + p;
            const unsigned short* sp = bp + ((long)n * 25600 + px) * recN + (s0 + 2 * h) * 8;
            short8 Bh = *reinterpret_cast<const short8*>(sp);
            short8 Bl = *reinterpret_cast<const short8*>(sp + 8);
            #pragma unroll
            for (int cc = 0; cc < 2; ++cc) {
                const unsigned short* fb = &frg[(rnd * 2 + cc) * 1024 + lane * 8];
                short8 Awh = *reinterpret_cast<const short8*>(fb);
                short8 Awl = *reinterpret_cast<const short8*>(fb + 512);
                acc[cc][k] = __builtin_amdgcn_mfma_f32_32x32x16_bf16(Awh, Bh, acc[cc][k], 0, 0, 0);
                acc[cc][k] = __builtin_amdgcn_mfma_f32_32x32x16_bf16(Awh, Bl, acc[cc][k], 0, 0, 0);
                acc[cc][k] = __builtin_amdgcn_mfma_f32_32x32x16_bf16(Awl, Bh, acc[cc][k], 0, 0, 0);
            }
        }
    }

    #pragma unroll
    for (int k = 0; k < 2; ++k) {
        const int px = px0 + (wv * 2 + k) * 32 + p;
        unsigned short* op;
        if (POUT) {
            const int y = px / 160, xx = px % 160;
            const int pl = (y & 1) * 2 + (xx & 1);
            op = outb + (((long)n * 4 + pl) * 6400 + (y >> 1) * 80 + (xx >> 1)) * 128;
        } else {
            op = outb + ((long)n * 25600 + px) * 128;
        }
        #pragma unroll
        for (int cc = 0; cc < 2; ++cc)
            #pragma unroll
            for (int q = 0; q < 4; ++q) {
                ushort4v hv, lv;
                #pragma unroll
                for (int r = 0; r < 4; ++r) {
                    float v = silu_f(acc[cc][k][q * 4 + r]);
                    unsigned short hh = bfhi(v);
                    hv[r] = hh; lv[r] = bfhi(v - bf2f(hh));
                }
                const int gq = cc * 4 + q;
                *reinterpret_cast<ushort4v*>(op + gq * 16 + 4 * h)     = hv;
                *reinterpret_cast<ushort4v*>(op + gq * 16 + 8 + 4 * h) = lv;
            }
    }
}

// ============ conv3: 64->128 s2 3x3, parity tiles, CIN-split 2 phases =======
// in h2 planes [n][4][6400][128ush]; out f32 NCHW d_out; PHASE0 raw, PHASE1 +silu
template <int PHASE>
__global__ __launch_bounds__(256, 2) void conv3_par(
    const unsigned short* __restrict__ h2p, const float* __restrict__ wraw,
    const float* __restrict__ bias, float* __restrict__ outf)
{
    __shared__ unsigned short lds[71712];        // tile 1089*32 ush + frags 36864 ush
    const int FB = 34848;
    const int tid = threadIdx.x;
    const int wv = tid >> 6, lane = tid & 63;
    const int p = lane & 31, h = lane >> 5;
    const int bx = blockIdx.x % 5, by = blockIdx.x / 5;
    const int ox0 = bx * 16, oy0 = by * 16;
    const int co0 = blockIdx.y * 64;
    const int n = blockIdx.z;

    for (int u = tid; u < 2304; u += 256) {      // pf=(tap*2+rnd)*2+cc
        const int l = u & 63, pf = u >> 6;
        const int cc = pf & 1, rnd = (pf >> 1) & 1, tap = pf >> 2;
        const int co = co0 + cc * 32 + (l & 31);
        const int ci0 = PHASE * 32 + rnd * 16 + (l >> 5) * 8;
        unsigned short hs[8], ls[8];
        #pragma unroll
        for (int j = 0; j < 8; ++j) {
            float wv_ = wraw[(co * 64 + ci0 + j) * 9 + tap];
            unsigned short hh = bfhi(wv_);
            hs[j] = hh; ls[j] = bfhi(wv_ - bf2f(hh));
        }
        *reinterpret_cast<short8*>(&lds[FB + pf * 1024 + l * 8])       = *(short8*)hs;
        *reinterpret_cast<short8*>(&lds[FB + pf * 1024 + 512 + l * 8]) = *(short8*)ls;
    }

    f32x16 acc[2][2];
    #pragma unroll
    for (int cc = 0; cc < 2; ++cc)
        #pragma unroll
        for (int q = 0; q < 4; ++q) {
            f32x4 b4 = {0.f, 0.f, 0.f, 0.f};
            if (PHASE == 0)
                b4 = *reinterpret_cast<const f32x4*>(&bias[co0 + cc * 32 + q * 8 + 4 * h]);
            #pragma unroll
            for (int r = 0; r < 4; ++r) { acc[cc][0][q*4+r] = b4[r]; acc[cc][1][q*4+r] = b4[r]; }
        }

    for (int rnd = 0; rnd < 2; ++rnd) {
        __syncthreads();
        // tiles: ee[0,256)W16, eo[256,528)W17, oe[528,800)W16, oo[800,1089)W17
        for (int u = tid; u < 4356; u += 256) {
            const int rec = u >> 2, s = u & 3;
            int gp, row, col;
            if (rec < 256)      { gp = 0; row = rec >> 4; col = rec & 15; }
            else if (rec < 528) { gp = 1; int r2 = rec - 256; row = r2 / 17; col = r2 - row * 17; }
            else if (rec < 800) { gp = 2; int r2 = rec - 528; row = r2 >> 4; col = r2 & 15; }
            else                { gp = 3; int r2 = rec - 800; row = r2 / 17; col = r2 - row * 17; }
            const int gr = (gp >= 2) ? oy0 - 1 + row : oy0 + row;
            const int gc = (gp & 1)  ? ox0 - 1 + col : ox0 + col;
            uint4v val = {0, 0, 0, 0};
            if (gr >= 0 && gr < 80 && gc >= 0 && gc < 80)
                val = *reinterpret_cast<const uint4v*>(
                    h2p + (((long)n * 4 + gp) * 6400 + gr * 80 + gc) * 128 + (PHASE * 8 + rnd * 4 + s) * 8);
            *reinterpret_cast<uint4v*>(&lds[rec * 32 + ((s ^ (rec & 3)) * 8)]) = val;
        }
        __syncthreads();

        #pragma unroll
        for (int tap = 0; tap < 9; ++tap) {
            const int dy = tap / 3 - 1, dx = tap % 3 - 1;
            const int ppy = dy & 1, ppx = dx & 1;
            const int gp = ppy * 2 + ppx;
            const int toy = ppy ? ((dy == -1) ? 0 : 1) : 0;
            const int tox = ppx ? ((dx == -1) ? 0 : 1) : 0;
            const int base = (gp == 0) ? 0 : (gp == 1) ? 256 : (gp == 2) ? 528 : 800;
            const int W = ppx ? 17 : 16;
            short8 Bh[2], Bl[2];
            #pragma unroll
            for (int k = 0; k < 2; ++k) {
                const int rl = (wv * 2 + k) * 2 + (p >> 4), cl = p & 15;
                const int rec = base + (ppy ? (rl + toy) : rl) * W + (cl + tox);
                const unsigned short* t = &lds[rec * 32];
                Bh[k] = *reinterpret_cast<const short8*>(t + (((2*h)     ^ (rec & 3)) * 8));
                Bl[k] = *reinterpret_cast<const short8*>(t + (((2*h + 1) ^ (rec & 3)) * 8));
            }
            #pragma unroll
            for (int cc = 0; cc < 2; ++cc) {
                const int pf = (tap * 2 + rnd) * 2 + cc;
                const unsigned short* fb = &lds[FB + pf * 1024 + lane * 8];
                short8 Awh = *reinterpret_cast<const short8*>(fb);
                short8 Awl = *reinterpret_cast<const short8*>(fb + 512);
                #pragma unroll
                for (int k = 0; k < 2; ++k) {
                    acc[cc][k] = __builtin_amdgcn_mfma_f32_32x32x16_bf16(Awh, Bh[k], acc[cc][k], 0, 0, 0);
                    acc[cc][k] = __builtin_amdgcn_mfma_f32_32x32x16_bf16(Awh, Bl[k], acc[cc][k], 0, 0, 0);
                    acc[cc][k] = __builtin_amdgcn_mfma_f32_32x32x16_bf16(Awl, Bh[k], acc[cc][k], 0, 0, 0);
                }
            }
        }
    }

    #pragma unroll
    for (int k = 0; k < 2; ++k) {
        const int oy = oy0 + (wv * 2 + k) * 2 + (p >> 4);
        const int pxg = oy * 80 + ox0 + (p & 15);
        #pragma unroll
        for (int cc = 0; cc < 2; ++cc)
            #pragma unroll
            for (int q = 0; q < 4; ++q)
                #pragma unroll
                for (int r = 0; r < 4; ++r) {
                    const int co = co0 + cc * 32 + q * 8 + 4 * h + r;
                    const long idx = ((long)n * 128 + co) * 6400 + pxg;
                    if (PHASE == 0) {
                        outf[idx] = acc[cc][k][q * 4 + r];
                    } else {
                        outf[idx] = silu_f(outf[idx] + acc[cc][k][q * 4 + r]);
                    }
                }
    }
}

extern "C" void kernel_launch(void* const* d_in, const int* in_sizes, int n_in,
                              void* d_out, int out_size, void* d_ws, size_t ws_size,
                              hipStream_t stream) {
    const float* x   = (const float*)d_in[0];
    const float* w0  = (const float*)d_in[1];
    const float* b0  = (const float*)d_in[2];
    const float* w1  = (const float*)d_in[3];
    const float* b1  = (const float*)d_in[4];
    const float* wc0 = (const float*)d_in[5];
    const float* bc0 = (const float*)d_in[6];
    const float* wb1 = (const float*)d_in[7];
    const float* bb1 = (const float*)d_in[8];
    const float* wb2 = (const float*)d_in[9];
    const float* bb2 = (const float*)d_in[10];
    const float* wc1 = (const float*)d_in[11];
    const float* bc1 = (const float*)d_in[12];
    const float* w3  = (const float*)d_in[13];
    const float* b3  = (const float*)d_in[14];

    unsigned short* u = (unsigned short*)d_ws;
    // ushort offsets; peak 157,286,400 bytes:
    //   h0p  [n][4][25600][64]  @ 0           (52,428,800 ush)
    //   h1   [n][25600][128]    @ 52,428,800  (26,214,400)
    //   ycl  [n][25600][128]    @ 0           (reuse h0p; h0p dead after conv1)
    //   b1cl [n][25600][64]     @ 26,214,400
    //   bcl  [n][25600][64]     @ 39,321,600
    //   h2p  [n][4][6400][128]  @ 52,428,800  (reuse h1; dead after wc0)
    unsigned short* h0p  = u;
    unsigned short* h1   = u + 52428800L;
    unsigned short* ycl  = u;
    unsigned short* b1cl = u + 26214400L;
    unsigned short* bcl  = u + 39321600L;
    unsigned short* h2p  = u + 52428800L;

    const dim3 blk(256, 1, 1);

    // conv0: 3->32 s2 f32-direct -> h0 parity planes
    conv0_par<<<dim3(100, 4, 8), blk, 0, stream>>>(x, w0, b0, h0p);

    // conv1: 32->64 s2 3x3 (parity MFMA) -> h1
    conv1_par<<<dim3(100, 1, 8), blk, 0, stream>>>(h0p, w1, b1, h1);

    // wc0: 1x1 64->64 -> ycl
    wc1x1<4, 0, false><<<dim3(100, 1, 8), blk, 0, stream>>>(
        h1, 128, h1, 128, wc0, bc0, ycl);

    // wb1: 3x3 s1 32->32 on x2 (ycl ch32-63, slot base 8) -> b1cl
    wb3x3<false><<<dim3(100, 1, 8), blk, 0, stream>>>(
        ycl, 128, 8, wb1, bb1, b1cl, nullptr);

    // wb2: 3x3 s1 32->32 on b1cl, + resid x2 -> bcl
    wb3x3<true><<<dim3(100, 1, 8), blk, 0, stream>>>(
        b1cl, 64, 0, wb2, bb2, bcl, ycl);

    // wc1: 1x1 concat(ycl 64, bcl 32) -> 64, parity-split out -> h2p
    wc1x1<4, 2, true><<<dim3(100, 1, 8), blk, 0, stream>>>(
        ycl, 128, bcl, 64, wc1, bc1, h2p);

    // conv3: 64->128 s2 3x3, CIN-split two phases -> d_out (f32 NCHW)
    conv3_par<0><<<dim3(25, 2, 8), blk, 0, stream>>>(h2p, w3, b3, (float*)d_out);
    conv3_par<1><<<dim3(25, 2, 8), blk, 0, stream>>>(h2p, w3, b3, (float*)d_out);
}

// Round 6
// 407.528 us; speedup vs baseline: 2.6833x; 1.1273x over previous
//
#include <hip/hip_runtime.h>
#include <hip/hip_bf16.h>

typedef __attribute__((ext_vector_type(8))) short short8;
typedef __attribute__((ext_vector_type(16))) float f32x16;
typedef __attribute__((ext_vector_type(4))) float f32x4;
typedef __attribute__((ext_vector_type(4))) unsigned int uint4v;
typedef __attribute__((ext_vector_type(4))) unsigned short ushort4v;

__device__ __forceinline__ float silu_f(float v) {
    return v * __builtin_amdgcn_rcpf(1.0f + __expf(-v));
}
__device__ __forceinline__ unsigned short bfhi(float v) {
    __hip_bfloat16 h = __float2bfloat16(v);
    return *reinterpret_cast<unsigned short*>(&h);
}
__device__ __forceinline__ float bf2f(unsigned short u) {
    __hip_bfloat16 h;
    *reinterpret_cast<unsigned short*>(&h) = u;
    return __bfloat162float(h);
}

// ============ conv0: 3->32 s2 f32-direct, writes PARITY-SPLIT hi/lo =========
__global__ __launch_bounds__(256) void conv0_par(
    const float* __restrict__ x, const float* __restrict__ w,
    const float* __restrict__ bias, unsigned short* __restrict__ out)
{
    const int tid = threadIdx.x;
    const int plane = blockIdx.y;
    const int pyp = plane >> 1, pxp = plane & 1;
    const int pp = blockIdx.x * 256 + tid;       // 0..25599
    const int n = blockIdx.z;
    const int Y = 2 * (pp / 160) + pyp, X = 2 * (pp % 160) + pxp;

    float acc[32];
    #pragma unroll
    for (int j = 0; j < 32; ++j) acc[j] = bias[j];

    const float* xp = x + (long)n * 3 * 409600;
    #pragma unroll
    for (int ci = 0; ci < 3; ++ci) {
        const float* pl = xp + (long)ci * 409600;
        float v[9];
        #pragma unroll
        for (int ky = 0; ky < 3; ++ky) {
            const int iy = 2 * Y + ky - 1;
            const bool yok = (iy >= 0) && (iy < 640);
            const int cy = yok ? iy : 0;
            #pragma unroll
            for (int kx = 0; kx < 3; ++kx) {
                const int ix = 2 * X + kx - 1;
                const bool ok = yok && (ix >= 0) && (ix < 640);
                float t = pl[(long)cy * 640 + (ok ? ix : 0)];
                v[ky * 3 + kx] = ok ? t : 0.0f;
            }
        }
        #pragma unroll
        for (int co = 0; co < 32; ++co) {
            const float* w9 = w + (co * 3 + ci) * 9;
            #pragma unroll
            for (int k = 0; k < 9; ++k) acc[co] += v[k] * w9[k];
        }
    }
    unsigned short* op = out + (((long)n * 4 + plane) * 25600 + pp) * 64;
    #pragma unroll
    for (int g = 0; g < 4; ++g) {
        unsigned int hw[4], lw[4];
        #pragma unroll
        for (int p2 = 0; p2 < 4; ++p2) {
            float v0 = silu_f(acc[g * 8 + p2 * 2]);
            float v1 = silu_f(acc[g * 8 + p2 * 2 + 1]);
            unsigned short h0 = bfhi(v0), h1 = bfhi(v1);
            hw[p2] = (unsigned)h0 | ((unsigned)h1 << 16);
            lw[p2] = (unsigned)bfhi(v0 - bf2f(h0)) | ((unsigned)bfhi(v1 - bf2f(h1)) << 16);
        }
        *reinterpret_cast<uint4v*>(op + g * 16)     = uint4v{hw[0], hw[1], hw[2], hw[3]};
        *reinterpret_cast<uint4v*>(op + g * 16 + 8) = uint4v{lw[0], lw[1], lw[2], lw[3]};
    }
}

// ============ conv1: 32->64 s2 3x3, parity-plane LDS tiles + MFMA ===========
// 512 threads = 8 waves; wave = 1 output row (32px), COW=64 (cc=2)
__global__ __launch_bounds__(512, 2) void conv1_par(
    const unsigned short* __restrict__ h0, const float* __restrict__ wraw,
    const float* __restrict__ bias, unsigned short* __restrict__ h1)
{
    __shared__ unsigned short lds[72224];        // tile 35360 ush + frags 36864 ush
    const int FB = 35360;
    const int tid = threadIdx.x;
    const int wv = tid >> 6, lane = tid & 63;
    const int p = lane & 31, h = lane >> 5;
    const int bx = blockIdx.x % 5, by = blockIdx.x / 5;
    const int ox0 = bx * 32, oy0 = by * 8;
    const int n = blockIdx.z;

    for (int u = tid; u < 2304; u += 512) {      // pf=(tap*2+rnd)*2+cc
        const int l = u & 63, pf = u >> 6;
        const int cc = pf & 1, rnd = (pf >> 1) & 1, tap = pf >> 2;
        const int co = cc * 32 + (l & 31);
        const int ci0 = rnd * 16 + (l >> 5) * 8;
        unsigned short hs[8], ls[8];
        #pragma unroll
        for (int j = 0; j < 8; ++j) {
            float wv_ = wraw[(co * 32 + ci0 + j) * 9 + tap];
            unsigned short hh = bfhi(wv_);
            hs[j] = hh; ls[j] = bfhi(wv_ - bf2f(hh));
        }
        *reinterpret_cast<short8*>(&lds[FB + pf * 1024 + l * 8])       = *(short8*)hs;
        *reinterpret_cast<short8*>(&lds[FB + pf * 1024 + 512 + l * 8]) = *(short8*)ls;
    }

    f32x16 acc[2];
    #pragma unroll
    for (int cc = 0; cc < 2; ++cc)
        #pragma unroll
        for (int q = 0; q < 4; ++q) {
            f32x4 b4 = *reinterpret_cast<const f32x4*>(&bias[cc * 32 + q * 8 + 4 * h]);
            #pragma unroll
            for (int r = 0; r < 4; ++r) acc[cc][q * 4 + r] = b4[r];
        }

    for (int rnd = 0; rnd < 2; ++rnd) {
        __syncthreads();
        // parity tiles: ee[0,256)W32, eo[256,520)W33, oe[520,808)W32, oo[808,1105)W33
        for (int u = tid; u < 4420; u += 512) {
            const int rec = u >> 2, s = u & 3;
            int gp, row, col;
            if (rec < 256)      { gp = 0; row = rec >> 5;  col = rec & 31; }
            else if (rec < 520) { gp = 1; int r2 = rec - 256; row = r2 / 33; col = r2 - row * 33; }
            else if (rec < 808) { gp = 2; int r2 = rec - 520; row = r2 >> 5; col = r2 & 31; }
            else                { gp = 3; int r2 = rec - 808; row = r2 / 33; col = r2 - row * 33; }
            const int gr = (gp >= 2) ? oy0 - 1 + row : oy0 + row;
            const int gc = (gp & 1)  ? ox0 - 1 + col : ox0 + col;
            uint4v val = {0, 0, 0, 0};
            if (gr >= 0 && gr < 160 && gc >= 0 && gc < 160)
                val = *reinterpret_cast<const uint4v*>(
                    h0 + (((long)n * 4 + gp) * 25600 + gr * 160 + gc) * 64 + (rnd * 4 + s) * 8);
            *reinterpret_cast<uint4v*>(&lds[rec * 32 + ((s ^ (rec & 3)) * 8)]) = val;
        }
        __syncthreads();

        #pragma unroll
        for (int tap = 0; tap < 9; ++tap) {
            const int dy = tap / 3 - 1, dx = tap % 3 - 1;
            const int ppy = dy & 1, ppx = dx & 1;
            const int gp = ppy * 2 + ppx;
            const int toy = ppy ? ((dy == -1) ? 0 : 1) : 0;
            const int tox = ppx ? ((dx == -1) ? 0 : 1) : 0;
            const int base = (gp == 0) ? 0 : (gp == 1) ? 256 : (gp == 2) ? 520 : 808;
            const int W = ppx ? 33 : 32;
            const int rec = base + (ppy ? (wv + toy) : wv) * W + (p + tox);
            const unsigned short* t = &lds[rec * 32];
            short8 Bh = *reinterpret_cast<const short8*>(t + (((2*h)     ^ (rec & 3)) * 8));
            short8 Bl = *reinterpret_cast<const short8*>(t + (((2*h + 1) ^ (rec & 3)) * 8));
            #pragma unroll
            for (int cc = 0; cc < 2; ++cc) {
                const int pf = (tap * 2 + rnd) * 2 + cc;
                const unsigned short* fb = &lds[FB + pf * 1024 + lane * 8];
                short8 Awh = *reinterpret_cast<const short8*>(fb);
                short8 Awl = *reinterpret_cast<const short8*>(fb + 512);
                acc[cc] = __builtin_amdgcn_mfma_f32_32x32x16_bf16(Awh, Bh, acc[cc], 0, 0, 0);
                acc[cc] = __builtin_amdgcn_mfma_f32_32x32x16_bf16(Awh, Bl, acc[cc], 0, 0, 0);
                acc[cc] = __builtin_amdgcn_mfma_f32_32x32x16_bf16(Awl, Bh, acc[cc], 0, 0, 0);
            }
        }
    }

    const int oy = oy0 + wv;
    unsigned short* op = h1 + ((long)n * 25600 + (long)oy * 160 + ox0 + p) * 128;
    #pragma unroll
    for (int cc = 0; cc < 2; ++cc)
        #pragma unroll
        for (int q = 0; q < 4; ++q) {
            ushort4v hv, lv;
            #pragma unroll
            for (int r = 0; r < 4; ++r) {
                float v = silu_f(acc[cc][q * 4 + r]);
                unsigned short hh = bfhi(v);
                hv[r] = hh; lv[r] = bfhi(v - bf2f(hh));
            }
            const int gq = cc * 4 + q;
            *reinterpret_cast<ushort4v*>(op + gq * 16 + 4 * h)     = hv;
            *reinterpret_cast<ushort4v*>(op + gq * 16 + 8 + 4 * h) = lv;
        }
}

// ============ wb: 32->32 s1 3x3, 512 threads, wave = 1 row ==================
template <bool RESID>
__global__ __launch_bounds__(512, 2) void wb3x3(
    const unsigned short* __restrict__ in, int inRec, int inSlot0,
    const float* __restrict__ wraw, const float* __restrict__ bias,
    unsigned short* __restrict__ outb, const unsigned short* __restrict__ resid)
{
    __shared__ unsigned short lds[40192];        // tile 340*64 ush + frags 18432 ush
    const int FB = 21760;
    const int tid = threadIdx.x;
    const int wv = tid >> 6, lane = tid & 63;
    const int p = lane & 31, h = lane >> 5;
    const int bx = blockIdx.x % 5, by = blockIdx.x / 5;
    const int ox0 = bx * 32, oy0 = by * 8;
    const int n = blockIdx.z;

    for (int u = tid; u < 1152; u += 512) {      // pf = tap*2+rnd (18) x 64
        const int l = u & 63, pf = u >> 6;
        const int rnd = pf & 1, tap = pf >> 1;
        const int co = l & 31;
        const int ci0 = rnd * 16 + (l >> 5) * 8;
        unsigned short hs[8], ls[8];
        #pragma unroll
        for (int j = 0; j < 8; ++j) {
            float wv_ = wraw[(co * 32 + ci0 + j) * 9 + tap];
            unsigned short hh = bfhi(wv_);
            hs[j] = hh; ls[j] = bfhi(wv_ - bf2f(hh));
        }
        *reinterpret_cast<short8*>(&lds[FB + pf * 1024 + l * 8])       = *(short8*)hs;
        *reinterpret_cast<short8*>(&lds[FB + pf * 1024 + 512 + l * 8]) = *(short8*)ls;
    }
    for (int u = tid; u < 2720; u += 512) {      // tile 34x10, 8 slots/rec
        const int rec = u >> 3, s = u & 7;
        const int row = rec / 34, col = rec - row * 34;
        const int gr = oy0 - 1 + row, gc = ox0 - 1 + col;
        uint4v val = {0, 0, 0, 0};
        if (gr >= 0 && gr < 160 && gc >= 0 && gc < 160)
            val = *reinterpret_cast<const uint4v*>(
                in + ((long)n * 25600 + gr * 160 + gc) * inRec + (inSlot0 + s) * 8);
        *reinterpret_cast<uint4v*>(&lds[rec * 64 + ((s ^ (rec & 7)) * 8)]) = val;
    }

    f32x16 acc;
    #pragma unroll
    for (int q = 0; q < 4; ++q) {
        f32x4 b4 = *reinterpret_cast<const f32x4*>(&bias[q * 8 + 4 * h]);
        #pragma unroll
        for (int r = 0; r < 4; ++r) acc[q * 4 + r] = b4[r];
    }
    __syncthreads();

    #pragma unroll
    for (int tap = 0; tap < 9; ++tap) {
        const int dy = tap / 3 - 1, dx = tap % 3 - 1;
        const int rec = (wv + dy + 1) * 34 + (p + dx + 1);
        const unsigned short* t = &lds[rec * 64];
        short8 Bh[2], Bl[2];
        #pragma unroll
        for (int rnd = 0; rnd < 2; ++rnd) {
            Bh[rnd] = *reinterpret_cast<const short8*>(t + (((rnd*4 + 2*h)     ^ (rec & 7)) * 8));
            Bl[rnd] = *reinterpret_cast<const short8*>(t + (((rnd*4 + 2*h + 1) ^ (rec & 7)) * 8));
        }
        #pragma unroll
        for (int rnd = 0; rnd < 2; ++rnd) {
            const unsigned short* fb = &lds[FB + (tap * 2 + rnd) * 1024 + lane * 8];
            short8 Awh = *reinterpret_cast<const short8*>(fb);
            short8 Awl = *reinterpret_cast<const short8*>(fb + 512);
            acc = __builtin_amdgcn_mfma_f32_32x32x16_bf16(Awh, Bh[rnd], acc, 0, 0, 0);
            acc = __builtin_amdgcn_mfma_f32_32x32x16_bf16(Awh, Bl[rnd], acc, 0, 0, 0);
            acc = __builtin_amdgcn_mfma_f32_32x32x16_bf16(Awl, Bh[rnd], acc, 0, 0, 0);
        }
    }

    const int oy = oy0 + wv;
    const long prow = (long)n * 25600 + (long)oy * 160 + ox0 + p;
    unsigned short* op = outb + prow * 64;
    const unsigned short* rp = RESID ? resid + prow * 128 : nullptr;
    #pragma unroll
    for (int q = 0; q < 4; ++q) {
        ushort4v hv, lv;
        float vs[4];
        #pragma unroll
        for (int r = 0; r < 4; ++r) vs[r] = silu_f(acc[q * 4 + r]);
        if (RESID) {
            ushort4v rh = *reinterpret_cast<const ushort4v*>(rp + (q + 4) * 16 + 4 * h);
            ushort4v rl = *reinterpret_cast<const ushort4v*>(rp + (q + 4) * 16 + 8 + 4 * h);
            #pragma unroll
            for (int r = 0; r < 4; ++r) vs[r] += bf2f(rh[r]) + bf2f(rl[r]);
        }
        #pragma unroll
        for (int r = 0; r < 4; ++r) {
            unsigned short hh = bfhi(vs[r]);
            hv[r] = hh; lv[r] = bfhi(vs[r] - bf2f(hh));
        }
        *reinterpret_cast<ushort4v*>(op + q * 16 + 4 * h)     = hv;
        *reinterpret_cast<ushort4v*>(op + q * 16 + 8 + 4 * h) = lv;
    }
}

// ============ 1x1 convs (wc0, wc1): 512 threads, direct global B-frags ======
template <int R1, int R2, bool POUT>
__global__ __launch_bounds__(512, 2) void wc1x1(
    const unsigned short* __restrict__ in1, int rec1,
    const unsigned short* __restrict__ in2, int rec2,
    const float* __restrict__ wraw, const float* __restrict__ bias,
    unsigned short* __restrict__ outb)
{
    constexpr int RT = R1 + R2;
    constexpr int CIN = RT * 16;
    __shared__ unsigned short frg[RT * 2 * 1024];
    const int tid = threadIdx.x;
    const int wv = tid >> 6, lane = tid & 63;
    const int p = lane & 31, h = lane >> 5;
    const int n = blockIdx.z;
    const int px0 = blockIdx.x * 512;

    for (int u = tid; u < RT * 2 * 64; u += 512) {
        const int l = u & 63, pf = u >> 6;       // pf = rnd*2+cc
        const int cc = pf & 1, rnd = pf >> 1;
        const int co = cc * 32 + (l & 31);
        const int ci0 = rnd * 16 + (l >> 5) * 8;
        unsigned short hs[8], ls[8];
        #pragma unroll
        for (int j = 0; j < 8; ++j) {
            float w = wraw[co * CIN + ci0 + j];
            unsigned short hh = bfhi(w);
            hs[j] = hh; ls[j] = bfhi(w - bf2f(hh));
        }
        *reinterpret_cast<short8*>(&frg[pf * 1024 + l * 8])       = *(short8*)hs;
        *reinterpret_cast<short8*>(&frg[pf * 1024 + 512 + l * 8]) = *(short8*)ls;
    }
    __syncthreads();

    f32x16 acc[2][2];
    #pragma unroll
    for (int cc = 0; cc < 2; ++cc)
        #pragma unroll
        for (int q = 0; q < 4; ++q) {
            f32x4 b4 = *reinterpret_cast<const f32x4*>(&bias[cc * 32 + q * 8 + 4 * h]);
            #pragma unroll
            for (int r = 0; r < 4; ++r) { acc[cc][0][q*4+r] = b4[r]; acc[cc][1][q*4+r] = b4[r]; }
        }

    #pragma unroll
    for (int rnd = 0; rnd < RT; ++rnd) {
        const unsigned short* bp = (rnd < R1) ? in1 : in2;
        const int recN = (rnd < R1) ? rec1 : rec2;
        const int s0 = 4 * ((rnd < R1) ? rnd : rnd - R1);
        #pragma unroll
        for (int k = 0; k < 2; ++k) {
            const int px = px0 + (wv * 2 + k) * 32 + p;
            const unsigned short* sp = bp + ((long)n * 25600 + px) * recN + (s0 + 2 * h) * 8;
            short8 Bh = *reinterpret_cast<const short8*>(sp);
            short8 Bl = *reinterpret_cast<const short8*>(sp + 8);
            #pragma unroll
            for (int cc = 0; cc < 2; ++cc) {
                const unsigned short* fb = &frg[(rnd * 2 + cc) * 1024 + lane * 8];
                short8 Awh = *reinterpret_cast<const short8*>(fb);
                short8 Awl = *reinterpret_cast<const short8*>(fb + 512);
                acc[cc][k] = __builtin_amdgcn_mfma_f32_32x32x16_bf16(Awh, Bh, acc[cc][k], 0, 0, 0);
                acc[cc][k] = __builtin_amdgcn_mfma_f32_32x32x16_bf16(Awh, Bl, acc[cc][k], 0, 0, 0);
                acc[cc][k] = __builtin_amdgcn_mfma_f32_32x32x16_bf16(Awl, Bh, acc[cc][k], 0, 0, 0);
            }
        }
    }

    #pragma unroll
    for (int k = 0; k < 2; ++k) {
        const int px = px0 + (wv * 2 + k) * 32 + p;
        unsigned short* op;
        if (POUT) {
            const int y = px / 160, xx = px % 160;
            const int pl = (y & 1) * 2 + (xx & 1);
            op = outb + (((long)n * 4 + pl) * 6400 + (y >> 1) * 80 + (xx >> 1)) * 128;
        } else {
            op = outb + ((long)n * 25600 + px) * 128;
        }
        #pragma unroll
        for (int cc = 0; cc < 2; ++cc)
            #pragma unroll
            for (int q = 0; q < 4; ++q) {
                ushort4v hv, lv;
                #pragma unroll
                for (int r = 0; r < 4; ++r) {
                    float v = silu_f(acc[cc][k][q * 4 + r]);
                    unsigned short hh = bfhi(v);
                    hv[r] = hh; lv[r] = bfhi(v - bf2f(hh));
                }
                const int gq = cc * 4 + q;
                *reinterpret_cast<ushort4v*>(op + gq * 16 + 4 * h)     = hv;
                *reinterpret_cast<ushort4v*>(op + gq * 16 + 8 + 4 * h) = lv;
            }
    }
}

// ============ conv3: 64->128 s2 3x3, 512 threads, wave = 32px chunk =========
template <int PHASE>
__global__ __launch_bounds__(512, 2) void conv3_par(
    const unsigned short* __restrict__ h2p, const float* __restrict__ wraw,
    const float* __restrict__ bias, float* __restrict__ outf)
{
    __shared__ unsigned short lds[71712];        // tile 1089*32 ush + frags 36864 ush
    const int FB = 34848;
    const int tid = threadIdx.x;
    const int wv = tid >> 6, lane = tid & 63;
    const int p = lane & 31, h = lane >> 5;
    const int bx = blockIdx.x % 5, by = blockIdx.x / 5;
    const int ox0 = bx * 16, oy0 = by * 16;
    const int co0 = blockIdx.y * 64;
    const int n = blockIdx.z;

    for (int u = tid; u < 2304; u += 512) {      // pf=(tap*2+rnd)*2+cc
        const int l = u & 63, pf = u >> 6;
        const int cc = pf & 1, rnd = (pf >> 1) & 1, tap = pf >> 2;
        const int co = co0 + cc * 32 + (l & 31);
        const int ci0 = PHASE * 32 + rnd * 16 + (l >> 5) * 8;
        unsigned short hs[8], ls[8];
        #pragma unroll
        for (int j = 0; j < 8; ++j) {
            float wv_ = wraw[(co * 64 + ci0 + j) * 9 + tap];
            unsigned short hh = bfhi(wv_);
            hs[j] = hh; ls[j] = bfhi(wv_ - bf2f(hh));
        }
        *reinterpret_cast<short8*>(&lds[FB + pf * 1024 + l * 8])       = *(short8*)hs;
        *reinterpret_cast<short8*>(&lds[FB + pf * 1024 + 512 + l * 8]) = *(short8*)ls;
    }

    f32x16 acc[2];
    #pragma unroll
    for (int cc = 0; cc < 2; ++cc)
        #pragma unroll
        for (int q = 0; q < 4; ++q) {
            f32x4 b4 = {0.f, 0.f, 0.f, 0.f};
            if (PHASE == 0)
                b4 = *reinterpret_cast<const f32x4*>(&bias[co0 + cc * 32 + q * 8 + 4 * h]);
            #pragma unroll
            for (int r = 0; r < 4; ++r) acc[cc][q * 4 + r] = b4[r];
        }

    for (int rnd = 0; rnd < 2; ++rnd) {
        __syncthreads();
        // tiles: ee[0,256)W16, eo[256,528)W17, oe[528,800)W16, oo[800,1089)W17
        for (int u = tid; u < 4356; u += 512) {
            const int rec = u >> 2, s = u & 3;
            int gp, row, col;
            if (rec < 256)      { gp = 0; row = rec >> 4; col = rec & 15; }
            else if (rec < 528) { gp = 1; int r2 = rec - 256; row = r2 / 17; col = r2 - row * 17; }
            else if (rec < 800) { gp = 2; int r2 = rec - 528; row = r2 >> 4; col = r2 & 15; }
            else                { gp = 3; int r2 = rec - 800; row = r2 / 17; col = r2 - row * 17; }
            const int gr = (gp >= 2) ? oy0 - 1 + row : oy0 + row;
            const int gc = (gp & 1)  ? ox0 - 1 + col : ox0 + col;
            uint4v val = {0, 0, 0, 0};
            if (gr >= 0 && gr < 80 && gc >= 0 && gc < 80)
                val = *reinterpret_cast<const uint4v*>(
                    h2p + (((long)n * 4 + gp) * 6400 + gr * 80 + gc) * 128 + (PHASE * 8 + rnd * 4 + s) * 8);
            *reinterpret_cast<uint4v*>(&lds[rec * 32 + ((s ^ (rec & 3)) * 8)]) = val;
        }
        __syncthreads();

        #pragma unroll
        for (int tap = 0; tap < 9; ++tap) {
            const int dy = tap / 3 - 1, dx = tap % 3 - 1;
            const int ppy = dy & 1, ppx = dx & 1;
            const int gp = ppy * 2 + ppx;
            const int toy = ppy ? ((dy == -1) ? 0 : 1) : 0;
            const int tox = ppx ? ((dx == -1) ? 0 : 1) : 0;
            const int base = (gp == 0) ? 0 : (gp == 1) ? 256 : (gp == 2) ? 528 : 800;
            const int W = ppx ? 17 : 16;
            const int rl = wv * 2 + (p >> 4), cl = p & 15;
            const int rec = base + (ppy ? (rl + toy) : rl) * W + (cl + tox);
            const unsigned short* t = &lds[rec * 32];
            short8 Bh = *reinterpret_cast<const short8*>(t + (((2*h)     ^ (rec & 3)) * 8));
            short8 Bl = *reinterpret_cast<const short8*>(t + (((2*h + 1) ^ (rec & 3)) * 8));
            #pragma unroll
            for (int cc = 0; cc < 2; ++cc) {
                const int pf = (tap * 2 + rnd) * 2 + cc;
                const unsigned short* fb = &lds[FB + pf * 1024 + lane * 8];
                short8 Awh = *reinterpret_cast<const short8*>(fb);
                short8 Awl = *reinterpret_cast<const short8*>(fb + 512);
                acc[cc] = __builtin_amdgcn_mfma_f32_32x32x16_bf16(Awh, Bh, acc[cc], 0, 0, 0);
                acc[cc] = __builtin_amdgcn_mfma_f32_32x32x16_bf16(Awh, Bl, acc[cc], 0, 0, 0);
                acc[cc] = __builtin_amdgcn_mfma_f32_32x32x16_bf16(Awl, Bh, acc[cc], 0, 0, 0);
            }
        }
    }

    const int rl = wv * 2 + (p >> 4);
    const int oy = oy0 + rl;
    const int pxg = oy * 80 + ox0 + (p & 15);
    #pragma unroll
    for (int cc = 0; cc < 2; ++cc)
        #pragma unroll
        for (int q = 0; q < 4; ++q)
            #pragma unroll
            for (int r = 0; r < 4; ++r) {
                const int co = co0 + cc * 32 + q * 8 + 4 * h + r;
                const long idx = ((long)n * 128 + co) * 6400 + pxg;
                if (PHASE == 0) {
                    outf[idx] = acc[cc][q * 4 + r];
                } else {
                    outf[idx] = silu_f(outf[idx] + acc[cc][q * 4 + r]);
                }
            }
}

extern "C" void kernel_launch(void* const* d_in, const int* in_sizes, int n_in,
                              void* d_out, int out_size, void* d_ws, size_t ws_size,
                              hipStream_t stream) {
    const float* x   = (const float*)d_in[0];
    const float* w0  = (const float*)d_in[1];
    const float* b0  = (const float*)d_in[2];
    const float* w1  = (const float*)d_in[3];
    const float* b1  = (const float*)d_in[4];
    const float* wc0 = (const float*)d_in[5];
    const float* bc0 = (const float*)d_in[6];
    const float* wb1 = (const float*)d_in[7];
    const float* bb1 = (const float*)d_in[8];
    const float* wb2 = (const float*)d_in[9];
    const float* bb2 = (const float*)d_in[10];
    const float* wc1 = (const float*)d_in[11];
    const float* bc1 = (const float*)d_in[12];
    const float* w3  = (const float*)d_in[13];
    const float* b3  = (const float*)d_in[14];

    unsigned short* u = (unsigned short*)d_ws;
    // ushort offsets; peak 157,286,400 bytes:
    //   h0p  [n][4][25600][64]  @ 0 ; h1 [n][25600][128] @ 52,428,800
    //   ycl @ 0 (reuse) ; b1cl @ 26,214,400 ; bcl @ 39,321,600 ; h2p @ 52,428,800
    unsigned short* h0p  = u;
    unsigned short* h1   = u + 52428800L;
    unsigned short* ycl  = u;
    unsigned short* b1cl = u + 26214400L;
    unsigned short* bcl  = u + 39321600L;
    unsigned short* h2p  = u + 52428800L;

    // conv0: 3->32 s2 f32-direct -> h0 parity planes
    conv0_par<<<dim3(100, 4, 8), dim3(256, 1, 1), 0, stream>>>(x, w0, b0, h0p);

    // conv1: 32->64 s2 3x3 (parity MFMA) -> h1
    conv1_par<<<dim3(100, 1, 8), dim3(512, 1, 1), 0, stream>>>(h0p, w1, b1, h1);

    // wc0: 1x1 64->64 -> ycl
    wc1x1<4, 0, false><<<dim3(50, 1, 8), dim3(512, 1, 1), 0, stream>>>(
        h1, 128, h1, 128, wc0, bc0, ycl);

    // wb1: 3x3 s1 32->32 on x2 (ycl ch32-63, slot base 8) -> b1cl
    wb3x3<false><<<dim3(100, 1, 8), dim3(512, 1, 1), 0, stream>>>(
        ycl, 128, 8, wb1, bb1, b1cl, nullptr);

    // wb2: 3x3 s1 32->32 on b1cl, + resid x2 -> bcl
    wb3x3<true><<<dim3(100, 1, 8), dim3(512, 1, 1), 0, stream>>>(
        b1cl, 64, 0, wb2, bb2, bcl, ycl);

    // wc1: 1x1 concat(ycl 64, bcl 32) -> 64, parity-split out -> h2p
    wc1x1<4, 2, true><<<dim3(50, 1, 8), dim3(512, 1, 1), 0, stream>>>(
        ycl, 128, bcl, 64, wc1, bc1, h2p);

    // conv3: 64->128 s2 3x3, CIN-split two phases -> d_out (f32 NCHW)
    conv3_par<0><<<dim3(25, 2, 8), dim3(512, 1, 1), 0, stream>>>(h2p, w3, b3, (float*)d_out);
    conv3_par<1><<<dim3(25, 2, 8), dim3(512, 1, 1), 0, stream>>>(h2p, w3, b3, (float*)d_out);
}

// Round 7
// 330.143 us; speedup vs baseline: 3.3122x; 1.2344x over previous
//
#include <hip/hip_runtime.h>
#include <hip/hip_bf16.h>

typedef __attribute__((ext_vector_type(8))) short short8;
typedef __attribute__((ext_vector_type(16))) float f32x16;
typedef __attribute__((ext_vector_type(4))) float f32x4;
typedef __attribute__((ext_vector_type(4))) unsigned int uint4v;
typedef __attribute__((ext_vector_type(4))) unsigned short ushort4v;

__device__ __forceinline__ float silu_f(float v) {
    return v * __builtin_amdgcn_rcpf(1.0f + __expf(-v));
}
__device__ __forceinline__ unsigned short bfhi(float v) {
    __hip_bfloat16 h = __float2bfloat16(v);
    return *reinterpret_cast<unsigned short*>(&h);
}
__device__ __forceinline__ float bf2f(unsigned short u) {
    __hip_bfloat16 h;
    *reinterpret_cast<unsigned short*>(&h) = u;
    return __bfloat162float(h);
}

// ======= weight prep: f32 -> bf16 hi/lo fragments (pf*1024 + lane*8, lo +512)
// arena1 (in d_out): conv1 @0 (36pf), wc0 @36 (8pf), wb1 @44 (18pf),
//                    wb2 @62 (18pf), wc1 @80 (12pf). 92 pf total.
__global__ __launch_bounds__(256) void prep_small(
    const float* __restrict__ w1, const float* __restrict__ wc0,
    const float* __restrict__ wb1, const float* __restrict__ wb2,
    const float* __restrict__ wc1, unsigned short* __restrict__ arena)
{
    const int u = blockIdx.x * 256 + threadIdx.x;   // 0..5887
    if (u >= 5888) return;
    const int lane = u & 63, pf = u >> 6;
    float wv[8];
    if (pf < 36) {
        const int q = pf, cc = q & 1, rnd = (q >> 1) & 1, tap = q >> 2;
        const int co = cc * 32 + (lane & 31), ci0 = rnd * 16 + (lane >> 5) * 8;
        #pragma unroll
        for (int j = 0; j < 8; ++j) wv[j] = w1[(co * 32 + ci0 + j) * 9 + tap];
    } else if (pf < 44) {
        const int q = pf - 36, cc = q & 1, rnd = q >> 1;
        const int co = cc * 32 + (lane & 31), ci0 = rnd * 16 + (lane >> 5) * 8;
        #pragma unroll
        for (int j = 0; j < 8; ++j) wv[j] = wc0[co * 64 + ci0 + j];
    } else if (pf < 62) {
        const int q = pf - 44, rnd = q & 1, tap = q >> 1;
        const int co = lane & 31, ci0 = rnd * 16 + (lane >> 5) * 8;
        #pragma unroll
        for (int j = 0; j < 8; ++j) wv[j] = wb1[(co * 32 + ci0 + j) * 9 + tap];
    } else if (pf < 80) {
        const int q = pf - 62, rnd = q & 1, tap = q >> 1;
        const int co = lane & 31, ci0 = rnd * 16 + (lane >> 5) * 8;
        #pragma unroll
        for (int j = 0; j < 8; ++j) wv[j] = wb2[(co * 32 + ci0 + j) * 9 + tap];
    } else {
        const int q = pf - 80, cc = q & 1, rnd = q >> 1;
        const int co = cc * 32 + (lane & 31), ci0 = rnd * 16 + (lane >> 5) * 8;
        #pragma unroll
        for (int j = 0; j < 8; ++j) wv[j] = wc1[co * 96 + ci0 + j];
    }
    unsigned short hs[8], ls[8];
    #pragma unroll
    for (int j = 0; j < 8; ++j) {
        unsigned short hh = bfhi(wv[j]);
        hs[j] = hh; ls[j] = bfhi(wv[j] - bf2f(hh));
    }
    *reinterpret_cast<short8*>(&arena[pf * 1024 + lane * 8])       = *(short8*)hs;
    *reinterpret_cast<short8*>(&arena[pf * 1024 + 512 + lane * 8]) = *(short8*)ls;
}

// arena2 (in ws, dead ycl region): w3, pf = ((cg*9+tap)*4 + PHASE*2+rnd)*2+cc, 144 pf
__global__ __launch_bounds__(256) void prep_w3(
    const float* __restrict__ w3, unsigned short* __restrict__ arena)
{
    const int u = blockIdx.x * 256 + threadIdx.x;   // 0..9215
    const int lane = u & 63, pf = u >> 6;
    const int cc = pf & 1, rnd2 = (pf >> 1) & 3, t9 = pf >> 3;
    const int tap = t9 % 9, cg = t9 / 9;
    const int co = cg * 64 + cc * 32 + (lane & 31);
    const int ci0 = (rnd2 >> 1) * 32 + (rnd2 & 1) * 16 + (lane >> 5) * 8;
    unsigned short hs[8], ls[8];
    #pragma unroll
    for (int j = 0; j < 8; ++j) {
        float wv = w3[(co * 64 + ci0 + j) * 9 + tap];
        unsigned short hh = bfhi(wv);
        hs[j] = hh; ls[j] = bfhi(wv - bf2f(hh));
    }
    *reinterpret_cast<short8*>(&arena[pf * 1024 + lane * 8])       = *(short8*)hs;
    *reinterpret_cast<short8*>(&arena[pf * 1024 + 512 + lane * 8]) = *(short8*)ls;
}

// ============ conv0: 3->32 s2 f32-direct, writes PARITY-SPLIT hi/lo =========
__global__ __launch_bounds__(256) void conv0_par(
    const float* __restrict__ x, const float* __restrict__ w,
    const float* __restrict__ bias, unsigned short* __restrict__ out)
{
    const int tid = threadIdx.x;
    const int plane = blockIdx.y;
    const int pyp = plane >> 1, pxp = plane & 1;
    const int pp = blockIdx.x * 256 + tid;
    const int n = blockIdx.z;
    const int Y = 2 * (pp / 160) + pyp, X = 2 * (pp % 160) + pxp;

    float acc[32];
    #pragma unroll
    for (int j = 0; j < 32; ++j) acc[j] = bias[j];

    const float* xp = x + (long)n * 3 * 409600;
    #pragma unroll
    for (int ci = 0; ci < 3; ++ci) {
        const float* pl = xp + (long)ci * 409600;
        float v[9];
        #pragma unroll
        for (int ky = 0; ky < 3; ++ky) {
            const int iy = 2 * Y + ky - 1;
            const bool yok = (iy >= 0) && (iy < 640);
            const int cy = yok ? iy : 0;
            #pragma unroll
            for (int kx = 0; kx < 3; ++kx) {
                const int ix = 2 * X + kx - 1;
                const bool ok = yok && (ix >= 0) && (ix < 640);
                float t = pl[(long)cy * 640 + (ok ? ix : 0)];
                v[ky * 3 + kx] = ok ? t : 0.0f;
            }
        }
        #pragma unroll
        for (int co = 0; co < 32; ++co) {
            const float* w9 = w + (co * 3 + ci) * 9;
            #pragma unroll
            for (int k = 0; k < 9; ++k) acc[co] += v[k] * w9[k];
        }
    }
    unsigned short* op = out + (((long)n * 4 + plane) * 25600 + pp) * 64;
    #pragma unroll
    for (int g = 0; g < 4; ++g) {
        unsigned int hw[4], lw[4];
        #pragma unroll
        for (int p2 = 0; p2 < 4; ++p2) {
            float v0 = silu_f(acc[g * 8 + p2 * 2]);
            float v1 = silu_f(acc[g * 8 + p2 * 2 + 1]);
            unsigned short h0 = bfhi(v0), h1 = bfhi(v1);
            hw[p2] = (unsigned)h0 | ((unsigned)h1 << 16);
            lw[p2] = (unsigned)bfhi(v0 - bf2f(h0)) | ((unsigned)bfhi(v1 - bf2f(h1)) << 16);
        }
        *reinterpret_cast<uint4v*>(op + g * 16)     = uint4v{hw[0], hw[1], hw[2], hw[3]};
        *reinterpret_cast<uint4v*>(op + g * 16 + 8) = uint4v{lw[0], lw[1], lw[2], lw[3]};
    }
}

// ============ conv1: 32->64 s2 3x3, tile-only LDS, frags from global ========
__global__ __launch_bounds__(512, 4) void conv1_par(
    const unsigned short* __restrict__ h0, const unsigned short* __restrict__ wfr,
    const float* __restrict__ bias, unsigned short* __restrict__ h1)
{
    __shared__ unsigned short lds[35360];        // parity tile only (70.7 KB)
    const int tid = threadIdx.x;
    const int wv = tid >> 6, lane = tid & 63;
    const int p = lane & 31, h = lane >> 5;
    const int bx = blockIdx.x % 5, by = blockIdx.x / 5;
    const int ox0 = bx * 32, oy0 = by * 8;
    const int n = blockIdx.z;

    f32x16 acc[2];
    #pragma unroll
    for (int cc = 0; cc < 2; ++cc)
        #pragma unroll
        for (int q = 0; q < 4; ++q) {
            f32x4 b4 = *reinterpret_cast<const f32x4*>(&bias[cc * 32 + q * 8 + 4 * h]);
            #pragma unroll
            for (int r = 0; r < 4; ++r) acc[cc][q * 4 + r] = b4[r];
        }

    for (int rnd = 0; rnd < 2; ++rnd) {
        __syncthreads();
        // parity tiles: ee[0,256)W32, eo[256,520)W33, oe[520,808)W32, oo[808,1105)W33
        for (int u = tid; u < 4420; u += 512) {
            const int rec = u >> 2, s = u & 3;
            int gp, row, col;
            if (rec < 256)      { gp = 0; row = rec >> 5;  col = rec & 31; }
            else if (rec < 520) { gp = 1; int r2 = rec - 256; row = r2 / 33; col = r2 - row * 33; }
            else if (rec < 808) { gp = 2; int r2 = rec - 520; row = r2 >> 5; col = r2 & 31; }
            else                { gp = 3; int r2 = rec - 808; row = r2 / 33; col = r2 - row * 33; }
            const int gr = (gp >= 2) ? oy0 - 1 + row : oy0 + row;
            const int gc = (gp & 1)  ? ox0 - 1 + col : ox0 + col;
            uint4v val = {0, 0, 0, 0};
            if (gr >= 0 && gr < 160 && gc >= 0 && gc < 160)
                val = *reinterpret_cast<const uint4v*>(
                    h0 + (((long)n * 4 + gp) * 25600 + gr * 160 + gc) * 64 + (rnd * 4 + s) * 8);
            *reinterpret_cast<uint4v*>(&lds[rec * 32 + ((s ^ (rec & 3)) * 8)]) = val;
        }
        __syncthreads();

        #pragma unroll
        for (int tap = 0; tap < 9; ++tap) {
            const int dy = tap / 3 - 1, dx = tap % 3 - 1;
            const int ppy = dy & 1, ppx = dx & 1;
            const int toy = ppy ? ((dy == -1) ? 0 : 1) : 0;
            const int tox = ppx ? ((dx == -1) ? 0 : 1) : 0;
            const int gp = ppy * 2 + ppx;
            const int base = (gp == 0) ? 0 : (gp == 1) ? 256 : (gp == 2) ? 520 : 808;
            const int W = ppx ? 33 : 32;
            const int rec = base + (ppy ? (wv + toy) : wv) * W + (p + tox);
            const unsigned short* t = &lds[rec * 32];
            short8 Bh = *reinterpret_cast<const short8*>(t + (((2*h)     ^ (rec & 3)) * 8));
            short8 Bl = *reinterpret_cast<const short8*>(t + (((2*h + 1) ^ (rec & 3)) * 8));
            #pragma unroll
            for (int cc = 0; cc < 2; ++cc) {
                const unsigned short* fb = wfr + ((tap * 2 + rnd) * 2 + cc) * 1024 + lane * 8;
                short8 Awh = *reinterpret_cast<const short8*>(fb);
                short8 Awl = *reinterpret_cast<const short8*>(fb + 512);
                acc[cc] = __builtin_amdgcn_mfma_f32_32x32x16_bf16(Awh, Bh, acc[cc], 0, 0, 0);
                acc[cc] = __builtin_amdgcn_mfma_f32_32x32x16_bf16(Awh, Bl, acc[cc], 0, 0, 0);
                acc[cc] = __builtin_amdgcn_mfma_f32_32x32x16_bf16(Awl, Bh, acc[cc], 0, 0, 0);
            }
        }
    }

    const int oy = oy0 + wv;
    unsigned short* op = h1 + ((long)n * 25600 + (long)oy * 160 + ox0 + p) * 128;
    #pragma unroll
    for (int cc = 0; cc < 2; ++cc)
        #pragma unroll
        for (int q = 0; q < 4; ++q) {
            ushort4v hv, lv;
            #pragma unroll
            for (int r = 0; r < 4; ++r) {
                float v = silu_f(acc[cc][q * 4 + r]);
                unsigned short hh = bfhi(v);
                hv[r] = hh; lv[r] = bfhi(v - bf2f(hh));
            }
            const int gq = cc * 4 + q;
            *reinterpret_cast<ushort4v*>(op + gq * 16 + 4 * h)     = hv;
            *reinterpret_cast<ushort4v*>(op + gq * 16 + 8 + 4 * h) = lv;
        }
}

// ============ wb: 32->32 s1 3x3, tile-only LDS, frags from global ===========
template <bool RESID>
__global__ __launch_bounds__(512, 4) void wb3x3(
    const unsigned short* __restrict__ in, int inRec, int inSlot0,
    const unsigned short* __restrict__ wfr, const float* __restrict__ bias,
    unsigned short* __restrict__ outb, const unsigned short* __restrict__ resid)
{
    __shared__ unsigned short lds[21760];        // tile 34x10 x 64 ush (43.5 KB)
    const int tid = threadIdx.x;
    const int wv = tid >> 6, lane = tid & 63;
    const int p = lane & 31, h = lane >> 5;
    const int bx = blockIdx.x % 5, by = blockIdx.x / 5;
    const int ox0 = bx * 32, oy0 = by * 8;
    const int n = blockIdx.z;

    for (int u = tid; u < 2720; u += 512) {      // tile 34x10, 8 slots/rec
        const int rec = u >> 3, s = u & 7;
        const int row = rec / 34, col = rec - row * 34;
        const int gr = oy0 - 1 + row, gc = ox0 - 1 + col;
        uint4v val = {0, 0, 0, 0};
        if (gr >= 0 && gr < 160 && gc >= 0 && gc < 160)
            val = *reinterpret_cast<const uint4v*>(
                in + ((long)n * 25600 + gr * 160 + gc) * inRec + (inSlot0 + s) * 8);
        *reinterpret_cast<uint4v*>(&lds[rec * 64 + ((s ^ (rec & 7)) * 8)]) = val;
    }

    f32x16 acc;
    #pragma unroll
    for (int q = 0; q < 4; ++q) {
        f32x4 b4 = *reinterpret_cast<const f32x4*>(&bias[q * 8 + 4 * h]);
        #pragma unroll
        for (int r = 0; r < 4; ++r) acc[q * 4 + r] = b4[r];
    }
    __syncthreads();

    #pragma unroll
    for (int tap = 0; tap < 9; ++tap) {
        const int dy = tap / 3 - 1, dx = tap % 3 - 1;
        const int rec = (wv + dy + 1) * 34 + (p + dx + 1);
        const unsigned short* t = &lds[rec * 64];
        short8 Bh[2], Bl[2];
        #pragma unroll
        for (int rnd = 0; rnd < 2; ++rnd) {
            Bh[rnd] = *reinterpret_cast<const short8*>(t + (((rnd*4 + 2*h)     ^ (rec & 7)) * 8));
            Bl[rnd] = *reinterpret_cast<const short8*>(t + (((rnd*4 + 2*h + 1) ^ (rec & 7)) * 8));
        }
        #pragma unroll
        for (int rnd = 0; rnd < 2; ++rnd) {
            const unsigned short* fb = wfr + (tap * 2 + rnd) * 1024 + lane * 8;
            short8 Awh = *reinterpret_cast<const short8*>(fb);
            short8 Awl = *reinterpret_cast<const short8*>(fb + 512);
            acc = __builtin_amdgcn_mfma_f32_32x32x16_bf16(Awh, Bh[rnd], acc, 0, 0, 0);
            acc = __builtin_amdgcn_mfma_f32_32x32x16_bf16(Awh, Bl[rnd], acc, 0, 0, 0);
            acc = __builtin_amdgcn_mfma_f32_32x32x16_bf16(Awl, Bh[rnd], acc, 0, 0, 0);
        }
    }

    const int oy = oy0 + wv;
    const long prow = (long)n * 25600 + (long)oy * 160 + ox0 + p;
    unsigned short* op = outb + prow * 64;
    const unsigned short* rp = RESID ? resid + prow * 128 : nullptr;
    #pragma unroll
    for (int q = 0; q < 4; ++q) {
        ushort4v hv, lv;
        float vs[4];
        #pragma unroll
        for (int r = 0; r < 4; ++r) vs[r] = silu_f(acc[q * 4 + r]);
        if (RESID) {
            ushort4v rh = *reinterpret_cast<const ushort4v*>(rp + (q + 4) * 16 + 4 * h);
            ushort4v rl = *reinterpret_cast<const ushort4v*>(rp + (q + 4) * 16 + 8 + 4 * h);
            #pragma unroll
            for (int r = 0; r < 4; ++r) vs[r] += bf2f(rh[r]) + bf2f(rl[r]);
        }
        #pragma unroll
        for (int r = 0; r < 4; ++r) {
            unsigned short hh = bfhi(vs[r]);
            hv[r] = hh; lv[r] = bfhi(vs[r] - bf2f(hh));
        }
        *reinterpret_cast<ushort4v*>(op + q * 16 + 4 * h)     = hv;
        *reinterpret_cast<ushort4v*>(op + q * 16 + 8 + 4 * h) = lv;
    }
}

// ============ 1x1 convs (wc0, wc1): zero LDS, frags from global =============
template <int R1, int R2, bool POUT>
__global__ __launch_bounds__(512, 4) void wc1x1(
    const unsigned short* __restrict__ in1, int rec1,
    const unsigned short* __restrict__ in2, int rec2,
    const unsigned short* __restrict__ wfr, const float* __restrict__ bias,
    unsigned short* __restrict__ outb)
{
    constexpr int RT = R1 + R2;
    const int tid = threadIdx.x;
    const int wv = tid >> 6, lane = tid & 63;
    const int p = lane & 31, h = lane >> 5;
    const int n = blockIdx.z;
    const int px0 = blockIdx.x * 512;

    f32x16 acc[2][2];
    #pragma unroll
    for (int cc = 0; cc < 2; ++cc)
        #pragma unroll
        for (int q = 0; q < 4; ++q) {
            f32x4 b4 = *reinterpret_cast<const f32x4*>(&bias[cc * 32 + q * 8 + 4 * h]);
            #pragma unroll
            for (int r = 0; r < 4; ++r) { acc[cc][0][q*4+r] = b4[r]; acc[cc][1][q*4+r] = b4[r]; }
        }

    #pragma unroll
    for (int rnd = 0; rnd < RT; ++rnd) {
        const unsigned short* bp = (rnd < R1) ? in1 : in2;
        const int recN = (rnd < R1) ? rec1 : rec2;
        const int s0 = 4 * ((rnd < R1) ? rnd : rnd - R1);
        #pragma unroll
        for (int k = 0; k < 2; ++k) {
            const int px = px0 + (wv * 2 + k) * 32 + p;
            const unsigned short* sp = bp + ((long)n * 25600 + px) * recN + (s0 + 2 * h) * 8;
            short8 Bh = *reinterpret_cast<const short8*>(sp);
            short8 Bl = *reinterpret_cast<const short8*>(sp + 8);
            #pragma unroll
            for (int cc = 0; cc < 2; ++cc) {
                const unsigned short* fb = wfr + (rnd * 2 + cc) * 1024 + lane * 8;
                short8 Awh = *reinterpret_cast<const short8*>(fb);
                short8 Awl = *reinterpret_cast<const short8*>(fb + 512);
                acc[cc][k] = __builtin_amdgcn_mfma_f32_32x32x16_bf16(Awh, Bh, acc[cc][k], 0, 0, 0);
                acc[cc][k] = __builtin_amdgcn_mfma_f32_32x32x16_bf16(Awh, Bl, acc[cc][k], 0, 0, 0);
                acc[cc][k] = __builtin_amdgcn_mfma_f32_32x32x16_bf16(Awl, Bh, acc[cc][k], 0, 0, 0);
            }
        }
    }

    #pragma unroll
    for (int k = 0; k < 2; ++k) {
        const int px = px0 + (wv * 2 + k) * 32 + p;
        unsigned short* op;
        if (POUT) {
            const int y = px / 160, xx = px % 160;
            const int pl = (y & 1) * 2 + (xx & 1);
            op = outb + (((long)n * 4 + pl) * 6400 + (y >> 1) * 80 + (xx >> 1)) * 128;
        } else {
            op = outb + ((long)n * 25600 + px) * 128;
        }
        #pragma unroll
        for (int cc = 0; cc < 2; ++cc)
            #pragma unroll
            for (int q = 0; q < 4; ++q) {
                ushort4v hv, lv;
                #pragma unroll
                for (int r = 0; r < 4; ++r) {
                    float v = silu_f(acc[cc][k][q * 4 + r]);
                    unsigned short hh = bfhi(v);
                    hv[r] = hh; lv[r] = bfhi(v - bf2f(hh));
                }
                const int gq = cc * 4 + q;
                *reinterpret_cast<ushort4v*>(op + gq * 16 + 4 * h)     = hv;
                *reinterpret_cast<ushort4v*>(op + gq * 16 + 8 + 4 * h) = lv;
            }
    }
}

// ============ conv3: 64->128 s2 3x3, tile-only LDS, frags from global =======
template <int PHASE>
__global__ __launch_bounds__(512, 4) void conv3_par(
    const unsigned short* __restrict__ h2p, const unsigned short* __restrict__ wfr,
    const float* __restrict__ bias, float* __restrict__ outf)
{
    __shared__ unsigned short lds[34848];        // tile 1089 x 32 ush (69.7 KB)
    const int tid = threadIdx.x;
    const int wv = tid >> 6, lane = tid & 63;
    const int p = lane & 31, h = lane >> 5;
    const int bx = blockIdx.x % 5, by = blockIdx.x / 5;
    const int ox0 = bx * 16, oy0 = by * 16;
    const int cg = blockIdx.y;
    const int co0 = cg * 64;
    const int n = blockIdx.z;

    f32x16 acc[2];
    #pragma unroll
    for (int cc = 0; cc < 2; ++cc)
        #pragma unroll
        for (int q = 0; q < 4; ++q) {
            f32x4 b4 = {0.f, 0.f, 0.f, 0.f};
            if (PHASE == 0)
                b4 = *reinterpret_cast<const f32x4*>(&bias[co0 + cc * 32 + q * 8 + 4 * h]);
            #pragma unroll
            for (int r = 0; r < 4; ++r) acc[cc][q * 4 + r] = b4[r];
        }

    for (int rnd = 0; rnd < 2; ++rnd) {
        __syncthreads();
        // tiles: ee[0,256)W16, eo[256,528)W17, oe[528,800)W16, oo[800,1089)W17
        for (int u = tid; u < 4356; u += 512) {
            const int rec = u >> 2, s = u & 3;
            int gp, row, col;
            if (rec < 256)      { gp = 0; row = rec >> 4; col = rec & 15; }
            else if (rec < 528) { gp = 1; int r2 = rec - 256; row = r2 / 17; col = r2 - row * 17; }
            else if (rec < 800) { gp = 2; int r2 = rec - 528; row = r2 >> 4; col = r2 & 15; }
            else                { gp = 3; int r2 = rec - 800; row = r2 / 17; col = r2 - row * 17; }
            const int gr = (gp >= 2) ? oy0 - 1 + row : oy0 + row;
            const int gc = (gp & 1)  ? ox0 - 1 + col : ox0 + col;
            uint4v val = {0, 0, 0, 0};
            if (gr >= 0 && gr < 80 && gc >= 0 && gc < 80)
                val = *reinterpret_cast<const uint4v*>(
                    h2p + (((long)n * 4 + gp) * 6400 + gr * 80 + gc) * 128 + (PHASE * 8 + rnd * 4 + s) * 8);
            *reinterpret_cast<uint4v*>(&lds[rec * 32 + ((s ^ (rec & 3)) * 8)]) = val;
        }
        __syncthreads();

        #pragma unroll
        for (int tap = 0; tap < 9; ++tap) {
            const int dy = tap / 3 - 1, dx = tap % 3 - 1;
            const int ppy = dy & 1, ppx = dx & 1;
            const int toy = ppy ? ((dy == -1) ? 0 : 1) : 0;
            const int tox = ppx ? ((dx == -1) ? 0 : 1) : 0;
            const int gp = ppy * 2 + ppx;
            const int base = (gp == 0) ? 0 : (gp == 1) ? 256 : (gp == 2) ? 528 : 800;
            const int W = ppx ? 17 : 16;
            const int rl = wv * 2 + (p >> 4), cl = p & 15;
            const int rec = base + (ppy ? (rl + toy) : rl) * W + (cl + tox);
            const unsigned short* t = &lds[rec * 32];
            short8 Bh = *reinterpret_cast<const short8*>(t + (((2*h)     ^ (rec & 3)) * 8));
            short8 Bl = *reinterpret_cast<const short8*>(t + (((2*h + 1) ^ (rec & 3)) * 8));
            #pragma unroll
            for (int cc = 0; cc < 2; ++cc) {
                const unsigned short* fb =
                    wfr + (((cg * 9 + tap) * 4 + PHASE * 2 + rnd) * 2 + cc) * 1024 + lane * 8;
                short8 Awh = *reinterpret_cast<const short8*>(fb);
                short8 Awl = *reinterpret_cast<const short8*>(fb + 512);
                acc[cc] = __builtin_amdgcn_mfma_f32_32x32x16_bf16(Awh, Bh, acc[cc], 0, 0, 0);
                acc[cc] = __builtin_amdgcn_mfma_f32_32x32x16_bf16(Awh, Bl, acc[cc], 0, 0, 0);
                acc[cc] = __builtin_amdgcn_mfma_f32_32x32x16_bf16(Awl, Bh, acc[cc], 0, 0, 0);
            }
        }
    }

    const int rl = wv * 2 + (p >> 4);
    const int oy = oy0 + rl;
    const int pxg = oy * 80 + ox0 + (p & 15);
    #pragma unroll
    for (int cc = 0; cc < 2; ++cc)
        #pragma unroll
        for (int q = 0; q < 4; ++q)
            #pragma unroll
            for (int r = 0; r < 4; ++r) {
                const int co = co0 + cc * 32 + q * 8 + 4 * h + r;
                const long idx = ((long)n * 128 + co) * 6400 + pxg;
                if (PHASE == 0) {
                    outf[idx] = acc[cc][q * 4 + r];
                } else {
                    outf[idx] = silu_f(outf[idx] + acc[cc][q * 4 + r]);
                }
            }
}

extern "C" void kernel_launch(void* const* d_in, const int* in_sizes, int n_in,
                              void* d_out, int out_size, void* d_ws, size_t ws_size,
                              hipStream_t stream) {
    const float* x   = (const float*)d_in[0];
    const float* w0  = (const float*)d_in[1];
    const float* b0  = (const float*)d_in[2];
    const float* w1  = (const float*)d_in[3];
    const float* b1  = (const float*)d_in[4];
    const float* wc0 = (const float*)d_in[5];
    const float* bc0 = (const float*)d_in[6];
    const float* wb1 = (const float*)d_in[7];
    const float* bb1 = (const float*)d_in[8];
    const float* wb2 = (const float*)d_in[9];
    const float* bb2 = (const float*)d_in[10];
    const float* wc1 = (const float*)d_in[11];
    const float* bc1 = (const float*)d_in[12];
    const float* w3  = (const float*)d_in[13];
    const float* b3  = (const float*)d_in[14];

    unsigned short* u = (unsigned short*)d_ws;
    // ws (ushort offsets), peak 157,286,400 B:
    //   h0p [n][4][25600][64] @0 ; h1 [n][25600][128] @52,428,800
    //   ycl @0 (reuse) ; b1cl @26,214,400 ; bcl @39,321,600 ; h2p @52,428,800
    //   w3 frag arena @0 (147,456 ush; written AFTER wc1 frees ycl)
    unsigned short* h0p  = u;
    unsigned short* h1   = u + 52428800L;
    unsigned short* ycl  = u;
    unsigned short* b1cl = u + 26214400L;
    unsigned short* bcl  = u + 39321600L;
    unsigned short* h2p  = u + 52428800L;
    unsigned short* w3a  = u;

    // small-conv frag arena lives in d_out (free until conv3 overwrites all of it)
    unsigned short* wsa = (unsigned short*)d_out;
    unsigned short* a_conv1 = wsa;
    unsigned short* a_wc0   = wsa + 36 * 1024;
    unsigned short* a_wb1   = wsa + 44 * 1024;
    unsigned short* a_wb2   = wsa + 62 * 1024;
    unsigned short* a_wc1   = wsa + 80 * 1024;

    // prep small-conv weight fragments -> d_out arena
    prep_small<<<dim3(23, 1, 1), dim3(256, 1, 1), 0, stream>>>(
        w1, wc0, wb1, wb2, wc1, wsa);

    // conv0: 3->32 s2 f32-direct -> h0 parity planes
    conv0_par<<<dim3(100, 4, 8), dim3(256, 1, 1), 0, stream>>>(x, w0, b0, h0p);

    // conv1: 32->64 s2 3x3 -> h1
    conv1_par<<<dim3(100, 1, 8), dim3(512, 1, 1), 0, stream>>>(h0p, a_conv1, b1, h1);

    // wc0: 1x1 64->64 -> ycl
    wc1x1<4, 0, false><<<dim3(50, 1, 8), dim3(512, 1, 1), 0, stream>>>(
        h1, 128, h1, 128, a_wc0, bc0, ycl);

    // wb1: 3x3 s1 32->32 on x2 (ycl ch32-63, slot base 8) -> b1cl
    wb3x3<false><<<dim3(100, 1, 8), dim3(512, 1, 1), 0, stream>>>(
        ycl, 128, 8, a_wb1, bb1, b1cl, nullptr);

    // wb2: 3x3 s1 32->32 on b1cl, + resid x2 -> bcl
    wb3x3<true><<<dim3(100, 1, 8), dim3(512, 1, 1), 0, stream>>>(
        b1cl, 64, 0, a_wb2, bb2, bcl, ycl);

    // wc1: 1x1 concat(ycl 64, bcl 32) -> 64, parity-split out -> h2p
    wc1x1<4, 2, true><<<dim3(50, 1, 8), dim3(512, 1, 1), 0, stream>>>(
        ycl, 128, bcl, 64, a_wc1, bc1, h2p);

    // prep w3 fragments -> ws arena (ycl region now dead)
    prep_w3<<<dim3(36, 1, 1), dim3(256, 1, 1), 0, stream>>>(w3, w3a);

    // conv3: 64->128 s2 3x3, CIN-split two phases -> d_out (f32 NCHW)
    conv3_par<0><<<dim3(25, 2, 8), dim3(512, 1, 1), 0, stream>>>(h2p, w3a, b3, (float*)d_out);
    conv3_par<1><<<dim3(25, 2, 8), dim3(512, 1, 1), 0, stream>>>(h2p, w3a, b3, (float*)d_out);
}

// Round 8
// 300.946 us; speedup vs baseline: 3.6335x; 1.0970x over previous
//
#include <hip/hip_runtime.h>
#include <hip/hip_bf16.h>

typedef __attribute__((ext_vector_type(8))) short short8;
typedef __attribute__((ext_vector_type(16))) float f32x16;
typedef __attribute__((ext_vector_type(4))) float f32x4;
typedef __attribute__((ext_vector_type(4))) unsigned int uint4v;
typedef __attribute__((ext_vector_type(4))) unsigned short ushort4v;

__device__ __forceinline__ float silu_f(float v) {
    return v * __builtin_amdgcn_rcpf(1.0f + __expf(-v));
}
__device__ __forceinline__ unsigned short bfhi(float v) {
    __hip_bfloat16 h = __float2bfloat16(v);
    return *reinterpret_cast<unsigned short*>(&h);
}
__device__ __forceinline__ float bf2f(unsigned short u) {
    __hip_bfloat16 h;
    *reinterpret_cast<unsigned short*>(&h) = u;
    return __bfloat162float(h);
}

// ======= weight prep: f32 -> bf16 hi/lo fragments (pf*1024 + lane*8, lo +512)
// arena (in d_out): conv1 @0 (36pf), wc0 @36 (8pf), wb1 @44 (18pf),
//   wb2 @62 (18pf), wc1 @80 (12pf), w0 @92 (2pf; K=32 padded from 27). 94 pf.
__global__ __launch_bounds__(256) void prep_small(
    const float* __restrict__ w1, const float* __restrict__ wc0,
    const float* __restrict__ wb1, const float* __restrict__ wb2,
    const float* __restrict__ wc1, const float* __restrict__ w0,
    unsigned short* __restrict__ arena)
{
    const int u = blockIdx.x * 256 + threadIdx.x;   // 0..6015
    if (u >= 6016) return;
    const int lane = u & 63, pf = u >> 6;
    float wv[8];
    if (pf < 36) {
        const int q = pf, cc = q & 1, rnd = (q >> 1) & 1, tap = q >> 2;
        const int co = cc * 32 + (lane & 31), ci0 = rnd * 16 + (lane >> 5) * 8;
        #pragma unroll
        for (int j = 0; j < 8; ++j) wv[j] = w1[(co * 32 + ci0 + j) * 9 + tap];
    } else if (pf < 44) {
        const int q = pf - 36, cc = q & 1, rnd = q >> 1;
        const int co = cc * 32 + (lane & 31), ci0 = rnd * 16 + (lane >> 5) * 8;
        #pragma unroll
        for (int j = 0; j < 8; ++j) wv[j] = wc0[co * 64 + ci0 + j];
    } else if (pf < 62) {
        const int q = pf - 44, rnd = q & 1, tap = q >> 1;
        const int co = lane & 31, ci0 = rnd * 16 + (lane >> 5) * 8;
        #pragma unroll
        for (int j = 0; j < 8; ++j) wv[j] = wb1[(co * 32 + ci0 + j) * 9 + tap];
    } else if (pf < 80) {
        const int q = pf - 62, rnd = q & 1, tap = q >> 1;
        const int co = lane & 31, ci0 = rnd * 16 + (lane >> 5) * 8;
        #pragma unroll
        for (int j = 0; j < 8; ++j) wv[j] = wb2[(co * 32 + ci0 + j) * 9 + tap];
    } else if (pf < 92) {
        const int q = pf - 80, cc = q & 1, rnd = q >> 1;
        const int co = cc * 32 + (lane & 31), ci0 = rnd * 16 + (lane >> 5) * 8;
        #pragma unroll
        for (int j = 0; j < 8; ++j) wv[j] = wc1[co * 96 + ci0 + j];
    } else {
        // w0 A-frags: k = (pf-92)*16 + (lane>>5)*8 + j ; k=ci*9+tap, pad k>=27
        const int co = lane & 31;
        const int k0 = (pf - 92) * 16 + (lane >> 5) * 8;
        #pragma unroll
        for (int j = 0; j < 8; ++j) {
            const int k = k0 + j;
            wv[j] = (k < 27) ? w0[(co * 3 + k / 9) * 9 + (k % 9)] : 0.0f;
        }
    }
    unsigned short hs[8], ls[8];
    #pragma unroll
    for (int j = 0; j < 8; ++j) {
        unsigned short hh = bfhi(wv[j]);
        hs[j] = hh; ls[j] = bfhi(wv[j] - bf2f(hh));
    }
    *reinterpret_cast<short8*>(&arena[pf * 1024 + lane * 8])       = *(short8*)hs;
    *reinterpret_cast<short8*>(&arena[pf * 1024 + 512 + lane * 8]) = *(short8*)ls;
}

// arena2 (in ws): w3, pf = ((cg*9+tap)*4 + PHASE*2+rnd)*2+cc, 144 pf
__global__ __launch_bounds__(256) void prep_w3(
    const float* __restrict__ w3, unsigned short* __restrict__ arena)
{
    const int u = blockIdx.x * 256 + threadIdx.x;   // 0..9215
    const int lane = u & 63, pf = u >> 6;
    const int cc = pf & 1, rnd2 = (pf >> 1) & 3, t9 = pf >> 3;
    const int tap = t9 % 9, cg = t9 / 9;
    const int co = cg * 64 + cc * 32 + (lane & 31);
    const int ci0 = (rnd2 >> 1) * 32 + (rnd2 & 1) * 16 + (lane >> 5) * 8;
    unsigned short hs[8], ls[8];
    #pragma unroll
    for (int j = 0; j < 8; ++j) {
        float wv = w3[(co * 64 + ci0 + j) * 9 + tap];
        unsigned short hh = bfhi(wv);
        hs[j] = hh; ls[j] = bfhi(wv - bf2f(hh));
    }
    *reinterpret_cast<short8*>(&arena[pf * 1024 + lane * 8])       = *(short8*)hs;
    *reinterpret_cast<short8*>(&arena[pf * 1024 + 512 + lane * 8]) = *(short8*)ls;
}

// ============ conv0: 3->32 s2 as K=32 gather-GEMM (MFMA), parity out ========
__global__ __launch_bounds__(512, 4) void conv0_mfma(
    const float* __restrict__ x, const unsigned short* __restrict__ wfr,
    const float* __restrict__ bias, unsigned short* __restrict__ out)
{
    const int tid = threadIdx.x;
    const int wv = tid >> 6, lane = tid & 63;
    const int p = lane & 31, h = lane >> 5;
    const int plane = blockIdx.y;
    const int pyp = plane >> 1, pxp = plane & 1;
    const int pp = blockIdx.x * 256 + wv * 32 + p;
    const int n = blockIdx.z;
    const int Y = 2 * (pp / 160) + pyp, X = 2 * (pp % 160) + pxp;

    // hoisted gather descriptors: 16 k-values per thread (k = rnd*16 + h*8 + j)
    int off[16]; float msk[16];
    #pragma unroll
    for (int rnd = 0; rnd < 2; ++rnd)
        #pragma unroll
        for (int j = 0; j < 8; ++j) {
            const int kidx = rnd * 16 + h * 8 + j;
            const int idx = rnd * 8 + j;
            if (kidx < 27) {
                const int ci = kidx / 9, tap = kidx - ci * 9;
                const int iy = 2 * Y + (tap / 3) - 1;
                const int ix = 2 * X + (tap % 3) - 1;
                const bool ok = (iy >= 0) && (iy < 640) && (ix >= 0) && (ix < 640);
                const int cy = min(max(iy, 0), 639), cx = min(max(ix, 0), 639);
                off[idx] = ci * 409600 + cy * 640 + cx;
                msk[idx] = ok ? 1.0f : 0.0f;
            } else {
                off[idx] = 0; msk[idx] = 0.0f;
            }
        }

    f32x16 acc;
    #pragma unroll
    for (int q = 0; q < 4; ++q) {
        f32x4 b4 = *reinterpret_cast<const f32x4*>(&bias[q * 8 + 4 * h]);
        #pragma unroll
        for (int r = 0; r < 4; ++r) acc[q * 4 + r] = b4[r];
    }

    const float* xb = x + (long)n * 1228800;
    #pragma unroll
    for (int rnd = 0; rnd < 2; ++rnd) {
        unsigned short hs[8], ls[8];
        #pragma unroll
        for (int j = 0; j < 8; ++j) {
            float v = xb[off[rnd * 8 + j]] * msk[rnd * 8 + j];
            unsigned short hh = bfhi(v);
            hs[j] = hh; ls[j] = bfhi(v - bf2f(hh));
        }
        short8 Bh = *(short8*)hs, Bl = *(short8*)ls;
        const unsigned short* fb = wfr + (92 + rnd) * 1024 + lane * 8;
        short8 Awh = *reinterpret_cast<const short8*>(fb);
        short8 Awl = *reinterpret_cast<const short8*>(fb + 512);
        acc = __builtin_amdgcn_mfma_f32_32x32x16_bf16(Awh, Bh, acc, 0, 0, 0);
        acc = __builtin_amdgcn_mfma_f32_32x32x16_bf16(Awh, Bl, acc, 0, 0, 0);
        acc = __builtin_amdgcn_mfma_f32_32x32x16_bf16(Awl, Bh, acc, 0, 0, 0);
    }

    unsigned short* op = out + (((long)n * 4 + plane) * 25600 + pp) * 64;
    #pragma unroll
    for (int q = 0; q < 4; ++q) {
        ushort4v hv, lv;
        #pragma unroll
        for (int r = 0; r < 4; ++r) {
            float v = silu_f(acc[q * 4 + r]);
            unsigned short hh = bfhi(v);
            hv[r] = hh; lv[r] = bfhi(v - bf2f(hh));
        }
        *reinterpret_cast<ushort4v*>(op + q * 16 + 4 * h)     = hv;
        *reinterpret_cast<ushort4v*>(op + q * 16 + 8 + 4 * h) = lv;
    }
}

// ============ conv1: 32->64 s2 3x3 + FUSED wc0 (1x1 64->64) ================
// K-loop from parity tiles; y = silu(conv1) staged to LDS; wc0 MFMAs; -> ycl
__global__ __launch_bounds__(512, 4) void conv1_fused(
    const unsigned short* __restrict__ h0, const unsigned short* __restrict__ wfr,
    const unsigned short* __restrict__ wc0fr, const float* __restrict__ bias,
    const float* __restrict__ bc0, unsigned short* __restrict__ ycl)
{
    __shared__ unsigned short lds[35360];        // parity tile / y-tile (70.7 KB)
    const int tid = threadIdx.x;
    const int wv = tid >> 6, lane = tid & 63;
    const int p = lane & 31, h = lane >> 5;
    const int bx = blockIdx.x % 5, by = blockIdx.x / 5;
    const int ox0 = bx * 32, oy0 = by * 8;
    const int n = blockIdx.z;

    f32x16 acc[2];
    #pragma unroll
    for (int cc = 0; cc < 2; ++cc)
        #pragma unroll
        for (int q = 0; q < 4; ++q) {
            f32x4 b4 = *reinterpret_cast<const f32x4*>(&bias[cc * 32 + q * 8 + 4 * h]);
            #pragma unroll
            for (int r = 0; r < 4; ++r) acc[cc][q * 4 + r] = b4[r];
        }

    for (int rnd = 0; rnd < 2; ++rnd) {
        __syncthreads();
        // parity tiles: ee[0,256)W32, eo[256,520)W33, oe[520,808)W32, oo[808,1105)W33
        for (int u = tid; u < 4420; u += 512) {
            const int rec = u >> 2, s = u & 3;
            int gp, row, col;
            if (rec < 256)      { gp = 0; row = rec >> 5;  col = rec & 31; }
            else if (rec < 520) { gp = 1; int r2 = rec - 256; row = r2 / 33; col = r2 - row * 33; }
            else if (rec < 808) { gp = 2; int r2 = rec - 520; row = r2 >> 5; col = r2 & 31; }
            else                { gp = 3; int r2 = rec - 808; row = r2 / 33; col = r2 - row * 33; }
            const int gr = (gp >= 2) ? oy0 - 1 + row : oy0 + row;
            const int gc = (gp & 1)  ? ox0 - 1 + col : ox0 + col;
            uint4v val = {0, 0, 0, 0};
            if (gr >= 0 && gr < 160 && gc >= 0 && gc < 160)
                val = *reinterpret_cast<const uint4v*>(
                    h0 + (((long)n * 4 + gp) * 25600 + gr * 160 + gc) * 64 + (rnd * 4 + s) * 8);
            *reinterpret_cast<uint4v*>(&lds[rec * 32 + ((s ^ (rec & 3)) * 8)]) = val;
        }
        __syncthreads();

        #pragma unroll
        for (int tap = 0; tap < 9; ++tap) {
            const int dy = tap / 3 - 1, dx = tap % 3 - 1;
            const int ppy = dy & 1, ppx = dx & 1;
            const int toy = ppy ? ((dy == -1) ? 0 : 1) : 0;
            const int tox = ppx ? ((dx == -1) ? 0 : 1) : 0;
            const int gp = ppy * 2 + ppx;
            const int base = (gp == 0) ? 0 : (gp == 1) ? 256 : (gp == 2) ? 520 : 808;
            const int W = ppx ? 33 : 32;
            const int rec = base + (ppy ? (wv + toy) : wv) * W + (p + tox);
            const unsigned short* t = &lds[rec * 32];
            short8 Bh = *reinterpret_cast<const short8*>(t + (((2*h)     ^ (rec & 3)) * 8));
            short8 Bl = *reinterpret_cast<const short8*>(t + (((2*h + 1) ^ (rec & 3)) * 8));
            #pragma unroll
            for (int cc = 0; cc < 2; ++cc) {
                const unsigned short* fb = wfr + ((tap * 2 + rnd) * 2 + cc) * 1024 + lane * 8;
                short8 Awh = *reinterpret_cast<const short8*>(fb);
                short8 Awl = *reinterpret_cast<const short8*>(fb + 512);
                acc[cc] = __builtin_amdgcn_mfma_f32_32x32x16_bf16(Awh, Bh, acc[cc], 0, 0, 0);
                acc[cc] = __builtin_amdgcn_mfma_f32_32x32x16_bf16(Awh, Bl, acc[cc], 0, 0, 0);
                acc[cc] = __builtin_amdgcn_mfma_f32_32x32x16_bf16(Awl, Bh, acc[cc], 0, 0, 0);
            }
        }
    }

    // ---- stage y = silu(conv1) into LDS as swizzled granules (rec = local px)
    __syncthreads();
    {
        const int rec = wv * 32 + p;
        #pragma unroll
        for (int cc = 0; cc < 2; ++cc)
            #pragma unroll
            for (int q = 0; q < 4; ++q) {
                ushort4v hv, lv;
                #pragma unroll
                for (int r = 0; r < 4; ++r) {
                    float v = silu_f(acc[cc][q * 4 + r]);
                    unsigned short hh = bfhi(v);
                    hv[r] = hh; lv[r] = bfhi(v - bf2f(hh));
                }
                const int gq = cc * 4 + q;
                const int slh = (2 * gq)     ^ (rec & 15);
                const int sll = (2 * gq + 1) ^ (rec & 15);
                *reinterpret_cast<ushort4v*>(&lds[rec * 128 + slh * 8 + 4 * h]) = hv;
                *reinterpret_cast<ushort4v*>(&lds[rec * 128 + sll * 8 + 4 * h]) = lv;
            }
    }
    __syncthreads();

    // ---- wc0: 1x1 64->64 from LDS y-tile
    f32x16 a2[2];
    #pragma unroll
    for (int cc = 0; cc < 2; ++cc)
        #pragma unroll
        for (int q = 0; q < 4; ++q) {
            f32x4 b4 = *reinterpret_cast<const f32x4*>(&bc0[cc * 32 + q * 8 + 4 * h]);
            #pragma unroll
            for (int r = 0; r < 4; ++r) a2[cc][q * 4 + r] = b4[r];
        }
    {
        const int rec = wv * 32 + p;
        #pragma unroll
        for (int rnd = 0; rnd < 4; ++rnd) {
            const int sh = (4 * rnd + 2 * h)     ^ (rec & 15);
            const int sl = (4 * rnd + 2 * h + 1) ^ (rec & 15);
            short8 Bh = *reinterpret_cast<const short8*>(&lds[rec * 128 + sh * 8]);
            short8 Bl = *reinterpret_cast<const short8*>(&lds[rec * 128 + sl * 8]);
            #pragma unroll
            for (int cc = 0; cc < 2; ++cc) {
                const unsigned short* fb = wc0fr + (rnd * 2 + cc) * 1024 + lane * 8;
                short8 Awh = *reinterpret_cast<const short8*>(fb);
                short8 Awl = *reinterpret_cast<const short8*>(fb + 512);
                a2[cc] = __builtin_amdgcn_mfma_f32_32x32x16_bf16(Awh, Bh, a2[cc], 0, 0, 0);
                a2[cc] = __builtin_amdgcn_mfma_f32_32x32x16_bf16(Awh, Bl, a2[cc], 0, 0, 0);
                a2[cc] = __builtin_amdgcn_mfma_f32_32x32x16_bf16(Awl, Bh, a2[cc], 0, 0, 0);
            }
        }
    }

    const int oy = oy0 + wv;
    unsigned short* op = ycl + ((long)n * 25600 + (long)oy * 160 + ox0 + p) * 128;
    #pragma unroll
    for (int cc = 0; cc < 2; ++cc)
        #pragma unroll
        for (int q = 0; q < 4; ++q) {
            ushort4v hv, lv;
            #pragma unroll
            for (int r = 0; r < 4; ++r) {
                float v = silu_f(a2[cc][q * 4 + r]);
                unsigned short hh = bfhi(v);
                hv[r] = hh; lv[r] = bfhi(v - bf2f(hh));
            }
            const int gq = cc * 4 + q;
            *reinterpret_cast<ushort4v*>(op + gq * 16 + 4 * h)     = hv;
            *reinterpret_cast<ushort4v*>(op + gq * 16 + 8 + 4 * h) = lv;
        }
}

// ============ wb: 32->32 s1 3x3, tile-only LDS, frags from global ===========
template <bool RESID>
__global__ __launch_bounds__(512, 4) void wb3x3(
    const unsigned short* __restrict__ in, int inRec, int inSlot0,
    const unsigned short* __restrict__ wfr, const float* __restrict__ bias,
    unsigned short* __restrict__ outb, const unsigned short* __restrict__ resid)
{
    __shared__ unsigned short lds[21760];        // tile 34x10 x 64 ush (43.5 KB)
    const int tid = threadIdx.x;
    const int wv = tid >> 6, lane = tid & 63;
    const int p = lane & 31, h = lane >> 5;
    const int bx = blockIdx.x % 5, by = blockIdx.x / 5;
    const int ox0 = bx * 32, oy0 = by * 8;
    const int n = blockIdx.z;

    for (int u = tid; u < 2720; u += 512) {      // tile 34x10, 8 slots/rec
        const int rec = u >> 3, s = u & 7;
        const int row = rec / 34, col = rec - row * 34;
        const int gr = oy0 - 1 + row, gc = ox0 - 1 + col;
        uint4v val = {0, 0, 0, 0};
        if (gr >= 0 && gr < 160 && gc >= 0 && gc < 160)
            val = *reinterpret_cast<const uint4v*>(
                in + ((long)n * 25600 + gr * 160 + gc) * inRec + (inSlot0 + s) * 8);
        *reinterpret_cast<uint4v*>(&lds[rec * 64 + ((s ^ (rec & 7)) * 8)]) = val;
    }

    f32x16 acc;
    #pragma unroll
    for (int q = 0; q < 4; ++q) {
        f32x4 b4 = *reinterpret_cast<const f32x4*>(&bias[q * 8 + 4 * h]);
        #pragma unroll
        for (int r = 0; r < 4; ++r) acc[q * 4 + r] = b4[r];
    }
    __syncthreads();

    #pragma unroll
    for (int tap = 0; tap < 9; ++tap) {
        const int dy = tap / 3 - 1, dx = tap % 3 - 1;
        const int rec = (wv + dy + 1) * 34 + (p + dx + 1);
        const unsigned short* t = &lds[rec * 64];
        short8 Bh[2], Bl[2];
        #pragma unroll
        for (int rnd = 0; rnd < 2; ++rnd) {
            Bh[rnd] = *reinterpret_cast<const short8*>(t + (((rnd*4 + 2*h)     ^ (rec & 7)) * 8));
            Bl[rnd] = *reinterpret_cast<const short8*>(t + (((rnd*4 + 2*h + 1) ^ (rec & 7)) * 8));
        }
        #pragma unroll
        for (int rnd = 0; rnd < 2; ++rnd) {
            const unsigned short* fb = wfr + (tap * 2 + rnd) * 1024 + lane * 8;
            short8 Awh = *reinterpret_cast<const short8*>(fb);
            short8 Awl = *reinterpret_cast<const short8*>(fb + 512);
            acc = __builtin_amdgcn_mfma_f32_32x32x16_bf16(Awh, Bh[rnd], acc, 0, 0, 0);
            acc = __builtin_amdgcn_mfma_f32_32x32x16_bf16(Awh, Bl[rnd], acc, 0, 0, 0);
            acc = __builtin_amdgcn_mfma_f32_32x32x16_bf16(Awl, Bh[rnd], acc, 0, 0, 0);
        }
    }

    const int oy = oy0 + wv;
    const long prow = (long)n * 25600 + (long)oy * 160 + ox0 + p;
    unsigned short* op = outb + prow * 64;
    const unsigned short* rp = RESID ? resid + prow * 128 : nullptr;
    #pragma unroll
    for (int q = 0; q < 4; ++q) {
        ushort4v hv, lv;
        float vs[4];
        #pragma unroll
        for (int r = 0; r < 4; ++r) vs[r] = silu_f(acc[q * 4 + r]);
        if (RESID) {
            ushort4v rh = *reinterpret_cast<const ushort4v*>(rp + (q + 4) * 16 + 4 * h);
            ushort4v rl = *reinterpret_cast<const ushort4v*>(rp + (q + 4) * 16 + 8 + 4 * h);
            #pragma unroll
            for (int r = 0; r < 4; ++r) vs[r] += bf2f(rh[r]) + bf2f(rl[r]);
        }
        #pragma unroll
        for (int r = 0; r < 4; ++r) {
            unsigned short hh = bfhi(vs[r]);
            hv[r] = hh; lv[r] = bfhi(vs[r] - bf2f(hh));
        }
        *reinterpret_cast<ushort4v*>(op + q * 16 + 4 * h)     = hv;
        *reinterpret_cast<ushort4v*>(op + q * 16 + 8 + 4 * h) = lv;
    }
}

// ============ wc1: 1x1 concat(96->64), zero LDS, frags from global ==========
template <int R1, int R2, bool POUT>
__global__ __launch_bounds__(512, 4) void wc1x1(
    const unsigned short* __restrict__ in1, int rec1,
    const unsigned short* __restrict__ in2, int rec2,
    const unsigned short* __restrict__ wfr, const float* __restrict__ bias,
    unsigned short* __restrict__ outb)
{
    constexpr int RT = R1 + R2;
    const int tid = threadIdx.x;
    const int wv = tid >> 6, lane = tid & 63;
    const int p = lane & 31, h = lane >> 5;
    const int n = blockIdx.z;
    const int px0 = blockIdx.x * 512;

    f32x16 acc[2][2];
    #pragma unroll
    for (int cc = 0; cc < 2; ++cc)
        #pragma unroll
        for (int q = 0; q < 4; ++q) {
            f32x4 b4 = *reinterpret_cast<const f32x4*>(&bias[cc * 32 + q * 8 + 4 * h]);
            #pragma unroll
            for (int r = 0; r < 4; ++r) { acc[cc][0][q*4+r] = b4[r]; acc[cc][1][q*4+r] = b4[r]; }
        }

    #pragma unroll
    for (int rnd = 0; rnd < RT; ++rnd) {
        const unsigned short* bp = (rnd < R1) ? in1 : in2;
        const int recN = (rnd < R1) ? rec1 : rec2;
        const int s0 = 4 * ((rnd < R1) ? rnd : rnd - R1);
        #pragma unroll
        for (int k = 0; k < 2; ++k) {
            const int px = px0 + (wv * 2 + k) * 32 + p;
            const unsigned short* sp = bp + ((long)n * 25600 + px) * recN + (s0 + 2 * h) * 8;
            short8 Bh = *reinterpret_cast<const short8*>(sp);
            short8 Bl = *reinterpret_cast<const short8*>(sp + 8);
            #pragma unroll
            for (int cc = 0; cc < 2; ++cc) {
                const unsigned short* fb = wfr + (rnd * 2 + cc) * 1024 + lane * 8;
                short8 Awh = *reinterpret_cast<const short8*>(fb);
                short8 Awl = *reinterpret_cast<const short8*>(fb + 512);
                acc[cc][k] = __builtin_amdgcn_mfma_f32_32x32x16_bf16(Awh, Bh, acc[cc][k], 0, 0, 0);
                acc[cc][k] = __builtin_amdgcn_mfma_f32_32x32x16_bf16(Awh, Bl, acc[cc][k], 0, 0, 0);
                acc[cc][k] = __builtin_amdgcn_mfma_f32_32x32x16_bf16(Awl, Bh, acc[cc][k], 0, 0, 0);
            }
        }
    }

    #pragma unroll
    for (int k = 0; k < 2; ++k) {
        const int px = px0 + (wv * 2 + k) * 32 + p;
        unsigned short* op;
        if (POUT) {
            const int y = px / 160, xx = px % 160;
            const int pl = (y & 1) * 2 + (xx & 1);
            op = outb + (((long)n * 4 + pl) * 6400 + (y >> 1) * 80 + (xx >> 1)) * 128;
        } else {
            op = outb + ((long)n * 25600 + px) * 128;
        }
        #pragma unroll
        for (int cc = 0; cc < 2; ++cc)
            #pragma unroll
            for (int q = 0; q < 4; ++q) {
                ushort4v hv, lv;
                #pragma unroll
                for (int r = 0; r < 4; ++r) {
                    float v = silu_f(acc[cc][k][q * 4 + r]);
                    unsigned short hh = bfhi(v);
                    hv[r] = hh; lv[r] = bfhi(v - bf2f(hh));
                }
                const int gq = cc * 4 + q;
                *reinterpret_cast<ushort4v*>(op + gq * 16 + 4 * h)     = hv;
                *reinterpret_cast<ushort4v*>(op + gq * 16 + 8 + 4 * h) = lv;
            }
    }
}

// ============ conv3: 64->128 s2 3x3, tile-only LDS, frags from global =======
template <int PHASE>
__global__ __launch_bounds__(512, 4) void conv3_par(
    const unsigned short* __restrict__ h2p, const unsigned short* __restrict__ wfr,
    const float* __restrict__ bias, float* __restrict__ outf)
{
    __shared__ unsigned short lds[34848];        // tile 1089 x 32 ush (69.7 KB)
    const int tid = threadIdx.x;
    const int wv = tid >> 6, lane = tid & 63;
    const int p = lane & 31, h = lane >> 5;
    const int bx = blockIdx.x % 5, by = blockIdx.x / 5;
    const int ox0 = bx * 16, oy0 = by * 16;
    const int cg = blockIdx.y;
    const int co0 = cg * 64;
    const int n = blockIdx.z;

    f32x16 acc[2];
    #pragma unroll
    for (int cc = 0; cc < 2; ++cc)
        #pragma unroll
        for (int q = 0; q < 4; ++q) {
            f32x4 b4 = {0.f, 0.f, 0.f, 0.f};
            if (PHASE == 0)
                b4 = *reinterpret_cast<const f32x4*>(&bias[co0 + cc * 32 + q * 8 + 4 * h]);
            #pragma unroll
            for (int r = 0; r < 4; ++r) acc[cc][q * 4 + r] = b4[r];
        }

    for (int rnd = 0; rnd < 2; ++rnd) {
        __syncthreads();
        for (int u = tid; u < 4356; u += 512) {
            const int rec = u >> 2, s = u & 3;
            int gp, row, col;
            if (rec < 256)      { gp = 0; row = rec >> 4; col = rec & 15; }
            else if (rec < 528) { gp = 1; int r2 = rec - 256; row = r2 / 17; col = r2 - row * 17; }
            else if (rec < 800) { gp = 2; int r2 = rec - 528; row = r2 >> 4; col = r2 & 15; }
            else                { gp = 3; int r2 = rec - 800; row = r2 / 17; col = r2 - row * 17; }
            const int gr = (gp >= 2) ? oy0 - 1 + row : oy0 + row;
            const int gc = (gp & 1)  ? ox0 - 1 + col : ox0 + col;
            uint4v val = {0, 0, 0, 0};
            if (gr >= 0 && gr < 80 && gc >= 0 && gc < 80)
                val = *reinterpret_cast<const uint4v*>(
                    h2p + (((long)n * 4 + gp) * 6400 + gr * 80 + gc) * 128 + (PHASE * 8 + rnd * 4 + s) * 8);
            *reinterpret_cast<uint4v*>(&lds[rec * 32 + ((s ^ (rec & 3)) * 8)]) = val;
        }
        __syncthreads();

        #pragma unroll
        for (int tap = 0; tap < 9; ++tap) {
            const int dy = tap / 3 - 1, dx = tap % 3 - 1;
            const int ppy = dy & 1, ppx = dx & 1;
            const int toy = ppy ? ((dy == -1) ? 0 : 1) : 0;
            const int tox = ppx ? ((dx == -1) ? 0 : 1) : 0;
            const int gp = ppy * 2 + ppx;
            const int base = (gp == 0) ? 0 : (gp == 1) ? 256 : (gp == 2) ? 528 : 800;
            const int W = ppx ? 17 : 16;
            const int rl = wv * 2 + (p >> 4), cl = p & 15;
            const int rec = base + (ppy ? (rl + toy) : rl) * W + (cl + tox);
            const unsigned short* t = &lds[rec * 32];
            short8 Bh = *reinterpret_cast<const short8*>(t + (((2*h)     ^ (rec & 3)) * 8));
            short8 Bl = *reinterpret_cast<const short8*>(t + (((2*h + 1) ^ (rec & 3)) * 8));
            #pragma unroll
            for (int cc = 0; cc < 2; ++cc) {
                const unsigned short* fb =
                    wfr + (((cg * 9 + tap) * 4 + PHASE * 2 + rnd) * 2 + cc) * 1024 + lane * 8;
                short8 Awh = *reinterpret_cast<const short8*>(fb);
                short8 Awl = *reinterpret_cast<const short8*>(fb + 512);
                acc[cc] = __builtin_amdgcn_mfma_f32_32x32x16_bf16(Awh, Bh, acc[cc], 0, 0, 0);
                acc[cc] = __builtin_amdgcn_mfma_f32_32x32x16_bf16(Awh, Bl, acc[cc], 0, 0, 0);
                acc[cc] = __builtin_amdgcn_mfma_f32_32x32x16_bf16(Awl, Bh, acc[cc], 0, 0, 0);
            }
        }
    }

    const int rl = wv * 2 + (p >> 4);
    const int oy = oy0 + rl;
    const int pxg = oy * 80 + ox0 + (p & 15);
    #pragma unroll
    for (int cc = 0; cc < 2; ++cc)
        #pragma unroll
        for (int q = 0; q < 4; ++q)
            #pragma unroll
            for (int r = 0; r < 4; ++r) {
                const int co = co0 + cc * 32 + q * 8 + 4 * h + r;
                const long idx = ((long)n * 128 + co) * 6400 + pxg;
                if (PHASE == 0) {
                    outf[idx] = acc[cc][q * 4 + r];
                } else {
                    outf[idx] = silu_f(outf[idx] + acc[cc][q * 4 + r]);
                }
            }
}

extern "C" void kernel_launch(void* const* d_in, const int* in_sizes, int n_in,
                              void* d_out, int out_size, void* d_ws, size_t ws_size,
                              hipStream_t stream) {
    const float* x   = (const float*)d_in[0];
    const float* w0  = (const float*)d_in[1];
    const float* b0  = (const float*)d_in[2];
    const float* w1  = (const float*)d_in[3];
    const float* b1  = (const float*)d_in[4];
    const float* wc0 = (const float*)d_in[5];
    const float* bc0 = (const float*)d_in[6];
    const float* wb1 = (const float*)d_in[7];
    const float* bb1 = (const float*)d_in[8];
    const float* wb2 = (const float*)d_in[9];
    const float* bb2 = (const float*)d_in[10];
    const float* wc1 = (const float*)d_in[11];
    const float* bc1 = (const float*)d_in[12];
    const float* w3  = (const float*)d_in[13];
    const float* b3  = (const float*)d_in[14];

    unsigned short* u = (unsigned short*)d_ws;
    // ws (ushort offsets), peak 157,286,400 B:
    //   h0p [n][4][25600][64] @0..52.4M      (dead after conv1_fused)
    //   ycl [n][25600][128]   @52,428,800..78,643,200
    //   b1cl [n][25600][64]   @26,214,400    (h0p dead)
    //   bcl  [n][25600][64]   @39,321,600
    //   h2p  [n][4][6400][128] @0            (h0p dead)
    //   w3a  @26,214,400                     (b1cl dead after wb2)
    unsigned short* h0p  = u;
    unsigned short* ycl  = u + 52428800L;
    unsigned short* b1cl = u + 26214400L;
    unsigned short* bcl  = u + 39321600L;
    unsigned short* h2p  = u;
    unsigned short* w3a  = u + 26214400L;

    // small-conv frag arena lives in d_out (conv3 phase0 overwrites it all)
    unsigned short* wsa = (unsigned short*)d_out;
    unsigned short* a_conv1 = wsa;
    unsigned short* a_wc0   = wsa + 36 * 1024;
    unsigned short* a_wb1   = wsa + 44 * 1024;
    unsigned short* a_wb2   = wsa + 62 * 1024;
    unsigned short* a_wc1   = wsa + 80 * 1024;

    // prep all small weight fragments (incl. w0 @ pf 92..93) -> d_out arena
    prep_small<<<dim3(24, 1, 1), dim3(256, 1, 1), 0, stream>>>(
        w1, wc0, wb1, wb2, wc1, w0, wsa);

    // conv0: 3->32 s2 gather-GEMM -> h0 parity planes
    conv0_mfma<<<dim3(100, 4, 8), dim3(512, 1, 1), 0, stream>>>(x, wsa, b0, h0p);

    // conv1 + fused wc0 -> ycl
    conv1_fused<<<dim3(100, 1, 8), dim3(512, 1, 1), 0, stream>>>(
        h0p, a_conv1, a_wc0, b1, bc0, ycl);

    // wb1: 3x3 s1 32->32 on x2 (ycl ch32-63, slot base 8) -> b1cl
    wb3x3<false><<<dim3(100, 1, 8), dim3(512, 1, 1), 0, stream>>>(
        ycl, 128, 8, a_wb1, bb1, b1cl, nullptr);

    // wb2: 3x3 s1 32->32 on b1cl, + resid x2 -> bcl
    wb3x3<true><<<dim3(100, 1, 8), dim3(512, 1, 1), 0, stream>>>(
        b1cl, 64, 0, a_wb2, bb2, bcl, ycl);

    // prep w3 fragments -> ws arena (b1cl dead after wb2)
    prep_w3<<<dim3(36, 1, 1), dim3(256, 1, 1), 0, stream>>>(w3, w3a);

    // wc1: 1x1 concat(ycl 64, bcl 32) -> 64, parity-split out -> h2p
    wc1x1<4, 2, true><<<dim3(50, 1, 8), dim3(512, 1, 1), 0, stream>>>(
        ycl, 128, bcl, 64, a_wc1, bc1, h2p);

    // conv3: 64->128 s2 3x3, CIN-split two phases -> d_out (f32 NCHW)
    conv3_par<0><<<dim3(25, 2, 8), dim3(512, 1, 1), 0, stream>>>(h2p, w3a, b3, (float*)d_out);
    conv3_par<1><<<dim3(25, 2, 8), dim3(512, 1, 1), 0, stream>>>(h2p, w3a, b3, (float*)d_out);
}